// Round 18
// baseline (581.535 us; speedup 1.0000x reference)
//
#include <hip/hip_runtime.h>

#define D     256
#define K     8192
#define NROWS 32768      // B*T
#define BETA  0.025f
#define TAU_NEW 2e-3f    // fp16 single-product margin (score err sigma ~2e-4)
#define TAU_OLD 2e-4f    // fp32 fallback path margin
#define RB    8          // fix1: rows per batch
#define KSP   2          // k-split ways

typedef _Float16 f16x8 __attribute__((ext_vector_type(8)));
typedef unsigned short ushort8v __attribute__((ext_vector_type(8)));
typedef float f32x16 __attribute__((ext_vector_type(16)));

#define MFMAH(a,b,c) __builtin_amdgcn_mfma_f32_32x32x16_f16(a,b,c,0,0,0)

// ---------------------------------------------------------------------------
// numpy-exact row sum-of-squares (pairwise_sum emulation, n=256); full rows
// ---------------------------------------------------------------------------
__global__ __launch_bounds__(256)
void np_sumsq_kernel(const float* __restrict__ src, float* __restrict__ dst,
                     int nrows) {
    const int tid  = threadIdx.x;
    const int w    = tid >> 6;
    const int lane = tid & 63;
    const int row  = blockIdx.x * 4 + w;
    if (row >= nrows) return;
    const float* a = src + (size_t)row * D;
    float r = 0.0f;
    if (lane < 16) {
        const float* h = a + (lane >> 3) * 128;
        const int j = lane & 7;
        float v = h[j];
        r = __fmul_rn(v, v);
        #pragma unroll
        for (int i = 8; i < 128; i += 8) {
            float u = h[i + j];
            r = __fadd_rn(r, __fmul_rn(u, u));
        }
    }
    float rr[16];
    #pragma unroll
    for (int t = 0; t < 16; ++t) rr[t] = __shfl(r, t, 64);
    if (lane == 0) {
        float h0 = __fadd_rn(__fadd_rn(__fadd_rn(rr[0], rr[1]), __fadd_rn(rr[2], rr[3])),
                             __fadd_rn(__fadd_rn(rr[4], rr[5]), __fadd_rn(rr[6], rr[7])));
        float h1 = __fadd_rn(__fadd_rn(__fadd_rn(rr[8], rr[9]), __fadd_rn(rr[10], rr[11])),
                             __fadd_rn(__fadd_rn(rr[12], rr[13]), __fadd_rn(rr[14], rr[15])));
        dst[row] = __fadd_rn(h0, h1);
    }
}

// Same, but only for flagged rows (x2 is needed only in the exact fixup).
__global__ __launch_bounds__(64)
void np_sumsq_flagged_kernel(const float* __restrict__ ze,
                             const int* __restrict__ nflag,
                             const int* __restrict__ flags,
                             float* __restrict__ x2, int cap) {
    const int lane = threadIdx.x;
    const int nf   = min(nflag[0], cap);
    for (int f = blockIdx.x; f < nf; f += gridDim.x) {
        const int row = flags[f];
        const float* a = ze + (size_t)row * D;
        float r = 0.0f;
        if (lane < 16) {
            const float* h = a + (lane >> 3) * 128;
            const int j = lane & 7;
            float v = h[j];
            r = __fmul_rn(v, v);
            #pragma unroll
            for (int i = 8; i < 128; i += 8) {
                float u = h[i + j];
                r = __fadd_rn(r, __fmul_rn(u, u));
            }
        }
        float rr[16];
        #pragma unroll
        for (int t = 0; t < 16; ++t) rr[t] = __shfl(r, t, 64);
        if (lane == 0) {
            float h0 = __fadd_rn(__fadd_rn(__fadd_rn(rr[0], rr[1]), __fadd_rn(rr[2], rr[3])),
                                 __fadd_rn(__fadd_rn(rr[4], rr[5]), __fadd_rn(rr[6], rr[7])));
            float h1 = __fadd_rn(__fadd_rn(__fadd_rn(rr[8], rr[9]), __fadd_rn(rr[10], rr[11])),
                                 __fadd_rn(__fadd_rn(rr[12], rr[13]), __fadd_rn(rr[14], rr[15])));
            x2[row] = __fadd_rn(h0, h1);
        }
    }
}

// ---------------------------------------------------------------------------
// Pack codebook into 32x32x16 f16 MFMA A-fragment order (single split).
// ushort offset = ((t*16 + c)*64 + l)*8 + j
// value = fp16( cb[t*32 + (l&31)][c*16 + 8*(l>>5) + j] )
// (k-slot map k = 8*(l>>5)+j identical for A and B -> k-permutation cancels.)
// ---------------------------------------------------------------------------
__global__ __launch_bounds__(256)
void pack_cb_kernel(const float* __restrict__ cb, unsigned short* __restrict__ cbp) {
    const int t  = blockIdx.x;          // 256 tiles of 32 codes
    const int l  = threadIdx.x & 63;
    const int cq = threadIdx.x >> 6;
    const int row = t * 32 + (l & 31);
    const int db  = 8 * (l >> 5);
    #pragma unroll
    for (int ci = 0; ci < 4; ++ci) {
        const int c  = cq * 4 + ci;
        const int d0 = c * 16 + db;
        float4 v0 = *reinterpret_cast<const float4*>(&cb[(size_t)row * D + d0]);
        float4 v1 = *reinterpret_cast<const float4*>(&cb[(size_t)row * D + d0 + 4]);
        float xv[8] = {v0.x, v0.y, v0.z, v0.w, v1.x, v1.y, v1.z, v1.w};
        f16x8 hv;
        #pragma unroll
        for (int j = 0; j < 8; ++j) hv[j] = (_Float16)xv[j];
        *reinterpret_cast<f16x8*>(cbp + (((size_t)t * 16 + c) * 64 + l) * 8) = hv;
    }
}

// ---------------------------------------------------------------------------
// MFMA distance GEMM + per-row top-2, fp16 single-product, 32x32x16.
// NO LDS; A-fragments loaded directly from global (coalesced uint4/lane);
// pure function of const inputs -> replay-deterministic by construction.
// ROUND-18: add a data-free __syncthreads() per tile. R15/R16/R17 all ~355us
// regardless of wave/grid shape: without barriers the 8 waves drift onto
// different tiles (8x16KB = 128KB >> 32KB L1) and every A-load thrashes to
// L2. The barrier has NO shared-data semantics (no LDS) — it only aligns
// waves onto the same tile so each 16KB tile is fetched from L2 once and
// served 8x from L1. Determinism unaffected.
// ---------------------------------------------------------------------------
__global__ __launch_bounds__(512)
void mfma_argmin_kernel(const float* __restrict__ ze,
                        const unsigned short* __restrict__ cbp,
                        const float* __restrict__ c2,
                        float2* __restrict__ tops, int* __restrict__ topi) {
    const int tid = threadIdx.x;
    const int l   = tid & 63;
    const int w   = tid >> 6;                   // 0..7
    const int ks  = blockIdx.x & (KSP - 1);
    const int nb  = blockIdx.x >> 1;            // log2(KSP)
    const int n   = nb * 256 + w * 32 + (l & 31);
    const int h   = l >> 5;

    // ---- z rows -> fp16 B fragments, register-resident (64 VGPR)
    f16x8 Bf[16];
    {
        const float* zr = ze + (size_t)n * D + 8 * h;
        #pragma unroll
        for (int c = 0; c < 16; ++c) {
            float4 v0 = *reinterpret_cast<const float4*>(zr + c * 16);
            float4 v1 = *reinterpret_cast<const float4*>(zr + c * 16 + 4);
            float xv[8] = {v0.x, v0.y, v0.z, v0.w, v1.x, v1.y, v1.z, v1.w};
            f16x8 hv;
            #pragma unroll
            for (int j = 0; j < 8; ++j) hv[j] = (_Float16)xv[j];
            Bf[c] = hv;
        }
    }

    const int NT = 256 / KSP;                   // tiles per block (128)
    const int t0 = ks * NT;
    const uint4* gsrc = reinterpret_cast<const uint4*>(cbp);  // tile = 1024 uint4

    float b1 = 3.4e38f, b2 = 3.4e38f;
    int   i1 = 0;

    for (int ti = 0; ti < NT; ++ti) {
        const int t = t0 + ti;
        const uint4* ab = gsrc + (size_t)t * 1024 + l;   // per-lane base

        f32x16 a0, a1;    // even / odd chunk chains
        #pragma unroll
        for (int i = 0; i < 16; ++i) { a0[i] = 0.0f; a1[i] = 0.0f; }
        #pragma unroll
        for (int c = 0; c < 16; c += 2) {
            uint4 r0 = ab[(c + 0) * 64];
            uint4 r1 = ab[(c + 1) * 64];
            a0 = MFMAH(__builtin_bit_cast(f16x8, r0), Bf[c + 0], a0);
            a1 = MFMAH(__builtin_bit_cast(f16x8, r1), Bf[c + 1], a1);
        }
        // epilogue: scores + running top-2 (codes ascend in processing order)
        // D mapping (m74/m101): col=l&31 (z-row), row=(reg&3)+8*(reg>>2)+4*h
        const float* c2t = c2 + t * 32 + 4 * h;
        const int base = t * 32 + 4 * h;
        #pragma unroll
        for (int g = 0; g < 4; ++g) {
            float4 cv = *reinterpret_cast<const float4*>(c2t + 8 * g);
            #pragma unroll
            for (int q = 0; q < 4; ++q) {
                const int reg = g * 4 + q;
                float dot = a0[reg] + a1[reg];
                float cc  = (q == 0) ? cv.x : (q == 1) ? cv.y : (q == 2) ? cv.z : cv.w;
                float s   = fmaf(-2.0f, dot, cc);
                int code  = base + 8 * g + q;
                bool lt = s < b1;
                b2 = fminf(b2, lt ? b1 : s);
                i1 = lt ? code : i1;
                b1 = lt ? s : b1;
            }
        }
        __syncthreads();   // data-free wave alignment: keep L1 tile-resident
    }

    // merge lane l <-> l^32 (same row n)
    float ob1 = __shfl_xor(b1, 32);
    float ob2 = __shfl_xor(b2, 32);
    int   oi1 = __shfl_xor(i1, 32);
    bool take = (ob1 < b1) || (ob1 == b1 && oi1 < i1);
    float nb2 = fminf(fmaxf(b1, ob1), fminf(b2, ob2));
    float nb1 = take ? ob1 : b1;
    int   ni1 = take ? oi1 : i1;
    if (l < 32) {
        tops[(size_t)n * KSP + ks] = make_float2(nb1, nb2);
        topi[(size_t)n * KSP + ks] = ni1;
    }
}

// ---------------------------------------------------------------------------
// Merge the KSP k-split top-2 entries per row; flag near-ties.
// ks ascending = code ranges ascending; strict '<' + index tie-break keeps
// np.argmin lowest-index semantics.
// ---------------------------------------------------------------------------
__global__ __launch_bounds__(256)
void ksplit_merge_kernel(const float2* __restrict__ tops, const int* __restrict__ topi,
                         int* __restrict__ idx_out, float* __restrict__ idxf_out,
                         int* __restrict__ nflag, int* __restrict__ flags, float tau) {
    const int n = blockIdx.x * 256 + threadIdx.x;
    float2 e0 = tops[(size_t)n * KSP + 0];
    float b1 = e0.x, b2 = e0.y;
    int   bi = topi[(size_t)n * KSP + 0];
    #pragma unroll
    for (int j = 1; j < KSP; ++j) {
        float2 ej = tops[(size_t)n * KSP + j];
        int    ij = topi[(size_t)n * KSP + j];
        bool take = (ej.x < b1) || (ej.x == b1 && ij < bi);
        b2 = fminf(fminf(b2, ej.y), take ? b1 : ej.x);
        b1 = take ? ej.x : b1;
        bi = take ? ij   : bi;
    }
    idx_out[n]  = bi;
    idxf_out[n] = (float)bi;
    if (b2 - b1 < tau) {
        int p = atomicAdd(nflag, 1);
        flags[p] = n;
    }
}

// ---------------------------------------------------------------------------
// Inverted-loop exact fixup, 16 row-stripes, 8-row batching (round-13 body,
// audited: coverage 512 cbblk x 16 stripes covers every (f,cbblk); writes
// scr[f*512+cbblk] disjoint; order-independent under flag permutation).
// ---------------------------------------------------------------------------
__global__ __launch_bounds__(256)
void fix1_kernel(const float* __restrict__ ze, const float* __restrict__ cb,
                 const float* __restrict__ c2, const float* __restrict__ x2,
                 const int* __restrict__ nflag, const int* __restrict__ flags,
                 float* __restrict__ scr_s, int* __restrict__ scr_i, int cap) {
    __shared__ float sz[RB][D];        // 8 KB
    __shared__ float sbest[RB][16];
    const int tid     = threadIdx.x;
    const int cl      = tid >> 4;
    const int dt      = tid & 15;
    const int cbblk   = blockIdx.x & 511;
    const int stripe  = blockIdx.x >> 9;
    const int nstripe = gridDim.x >> 9;    // 16
    const int code    = cbblk * 16 + cl;
    const int nf      = min(nflag[0], cap);
    if (nf == 0) return;
    const int perStripe = (nf - stripe + nstripe - 1) / nstripe;
    if (perStripe <= 0) return;
    // hoist this block's cb slice into fp64 registers (once per block)
    double cbr[16];
    {
        const float* crp = cb + (size_t)code * D + dt;
        #pragma unroll
        for (int j = 0; j < 16; ++j) cbr[j] = (double)crp[16 * j];
    }
    const float cc = c2[code];
    for (int it = 0; it < perStripe; it += RB) {
        __syncthreads();                       // prev batch's scan done
        #pragma unroll
        for (int r = 0; r < RB; ++r) {
            if (it + r < perStripe) {
                const int row = flags[stripe + nstripe * (it + r)];
                sz[r][tid] = ze[(size_t)row * D + tid];
            }
        }
        __syncthreads();                       // sz visible
        #pragma unroll
        for (int r = 0; r < RB; ++r) {
            if (it + r < perStripe) {
                double dot = 0.0;
                #pragma unroll
                for (int j = 0; j < 16; ++j)
                    dot = fma((double)sz[r][dt + 16 * j], cbr[j], dot);
                #pragma unroll
                for (int o = 1; o < 16; o <<= 1)
                    dot += __shfl_xor(dot, o);
                if (dt == 0) {
                    const int f = stripe + nstripe * (it + r);
                    float P  = (float)dot;
                    float t3 = __fadd_rn(x2[flags[f]], __fmul_rn(-2.0f, P));
                    sbest[r][cl] = __fadd_rn(t3, cc);
                }
            }
        }
        __syncthreads();                       // sbest visible
        if (tid < RB && it + tid < perStripe) {
            const int f = stripe + nstripe * (it + tid);
            float bs = sbest[tid][0]; int bc = 0;
            #pragma unroll
            for (int c = 1; c < 16; ++c)
                if (sbest[tid][c] < bs) { bs = sbest[tid][c]; bc = c; }
            scr_s[(size_t)f * 512 + cbblk] = bs;
            scr_i[(size_t)f * 512 + cbblk] = cbblk * 16 + bc;
        }
    }
}

__global__ __launch_bounds__(256)
void fix2_kernel(const int* __restrict__ nflag, const int* __restrict__ flags,
                 const float* __restrict__ scr_s, const int* __restrict__ scr_i,
                 int* __restrict__ idx_out, float* __restrict__ idxf_out, int cap) {
    __shared__ float ss[256];
    __shared__ int   si[256];
    const int tid = threadIdx.x;
    const int nf  = min(nflag[0], cap);
    for (int f = blockIdx.x; f < nf; f += gridDim.x) {
        float s0 = scr_s[(size_t)f * 512 + tid];
        int   j0 = scr_i[(size_t)f * 512 + tid];
        float s1 = scr_s[(size_t)f * 512 + 256 + tid];
        int   j1 = scr_i[(size_t)f * 512 + 256 + tid];
        bool take = (s1 < s0) || (s1 == s0 && j1 < j0);
        ss[tid] = take ? s1 : s0;
        si[tid] = take ? j1 : j0;
        __syncthreads();
        for (int o = 128; o; o >>= 1) {
            if (tid < o) {
                if (ss[tid + o] < ss[tid] ||
                    (ss[tid + o] == ss[tid] && si[tid + o] < si[tid])) {
                    ss[tid] = ss[tid + o]; si[tid] = si[tid + o];
                }
            }
            __syncthreads();
        }
        if (tid == 0) {
            const int row = flags[f];
            idx_out[row]  = si[0];
            idxf_out[row] = (float)si[0];
        }
        __syncthreads();
    }
}

// ---------------------------------------------------------------------------
// FALLBACK (round-3 verified): fp32 vector GEMM + top-2, fp64 fixup.
// ---------------------------------------------------------------------------
__global__ __launch_bounds__(512)
void argmin_fp32_kernel(const float* __restrict__ ze, const float* __restrict__ cb,
                        const float* __restrict__ c2,
                        int* __restrict__ idx_out, float* __restrict__ idxf_out,
                        int* __restrict__ nflag, int* __restrict__ flags) {
    __shared__ float smem[12672];
    float* a_s = smem;
    float* b_s = smem + 32 * 128;
    const int tid  = threadIdx.x;
    const int tx   = tid & 31;
    const int ty   = tid >> 5;
    const int row0 = blockIdx.x * 128;
    float b1[8], b2[8];
    int   i1[8];
    #pragma unroll
    for (int r = 0; r < 8; ++r) { b1[r] = 3.4e38f; b2[r] = 3.4e38f; i1[r] = 0; }
    for (int kt = 0; kt < K; kt += 256) {
        float acc[8][8];
        #pragma unroll
        for (int r = 0; r < 8; ++r)
            #pragma unroll
            for (int c = 0; c < 8; ++c) acc[r][c] = 0.0f;
        for (int dc = 0; dc < D; dc += 32) {
            __syncthreads();
            #pragma unroll
            for (int j = 0; j < 2; ++j) {
                int p = tid + j * 512, ar = p >> 3, ad = (p & 7) << 2;
                float4 v = *reinterpret_cast<const float4*>(&ze[(size_t)(row0 + ar) * D + dc + ad]);
                a_s[(ad + 0) * 128 + ar] = v.x; a_s[(ad + 1) * 128 + ar] = v.y;
                a_s[(ad + 2) * 128 + ar] = v.z; a_s[(ad + 3) * 128 + ar] = v.w;
            }
            #pragma unroll
            for (int j = 0; j < 4; ++j) {
                int p = tid + j * 512, br = p >> 3, bd = (p & 7) << 2;
                float4 v = *reinterpret_cast<const float4*>(&cb[(size_t)(kt + br) * D + dc + bd]);
                b_s[(bd + 0) * 256 + br] = v.x; b_s[(bd + 1) * 256 + br] = v.y;
                b_s[(bd + 2) * 256 + br] = v.z; b_s[(bd + 3) * 256 + br] = v.w;
            }
            __syncthreads();
            #pragma unroll 4
            for (int d = 0; d < 32; ++d) {
                float4 a0  = *reinterpret_cast<const float4*>(&a_s[d * 128 + ty * 4]);
                float4 a1  = *reinterpret_cast<const float4*>(&a_s[d * 128 + 64 + ty * 4]);
                float4 b0  = *reinterpret_cast<const float4*>(&b_s[d * 256 + tx * 4]);
                float4 b1v = *reinterpret_cast<const float4*>(&b_s[d * 256 + 128 + tx * 4]);
                float av[8] = {a0.x, a0.y, a0.z, a0.w, a1.x, a1.y, a1.z, a1.w};
                float bv[8] = {b0.x, b0.y, b0.z, b0.w, b1v.x, b1v.y, b1v.z, b1v.w};
                #pragma unroll
                for (int r = 0; r < 8; ++r)
                    #pragma unroll
                    for (int c = 0; c < 8; ++c)
                        acc[r][c] = fmaf(av[r], bv[c], acc[r][c]);
            }
        }
        float4 cs0 = *reinterpret_cast<const float4*>(&c2[kt + tx * 4]);
        float4 cs1 = *reinterpret_cast<const float4*>(&c2[kt + 128 + tx * 4]);
        float cv[8] = {cs0.x, cs0.y, cs0.z, cs0.w, cs1.x, cs1.y, cs1.z, cs1.w};
        #pragma unroll
        for (int r = 0; r < 8; ++r)
            #pragma unroll
            for (int c = 0; c < 8; ++c) {
                int col = kt + ((c < 4) ? (tx * 4 + c) : (128 + tx * 4 + (c - 4)));
                float s = fmaf(-2.0f, acc[r][c], cv[c]);
                if (s < b1[r]) { b2[r] = b1[r]; b1[r] = s; i1[r] = col; }
                else if (s < b2[r]) { b2[r] = s; }
            }
    }
    __syncthreads();
    float* rs1 = smem;
    int*   ri  = (int*)(smem + 4224);
    float* rs2 = smem + 8448;
    #pragma unroll
    for (int r = 0; r < 8; ++r) {
        int lrow = (r >> 2) * 64 + ty * 4 + (r & 3);
        rs1[lrow * 33 + tx] = b1[r]; ri[lrow * 33 + tx] = i1[r]; rs2[lrow * 33 + tx] = b2[r];
    }
    __syncthreads();
    if (tid < 128) {
        float B1 = 3.4e38f, B2 = 3.4e38f;
        int I1 = 0;
        #pragma unroll 4
        for (int t = 0; t < 32; ++t) {
            float s1 = rs1[tid * 33 + t]; int j1 = ri[tid * 33 + t]; float s2 = rs2[tid * 33 + t];
            if (s1 < B1 || (s1 == B1 && j1 < I1)) { B2 = fminf(B2, B1); B1 = s1; I1 = j1; }
            else B2 = fminf(B2, s1);
            B2 = fminf(B2, s2);
        }
        int grow = row0 + tid;
        idx_out[grow] = I1;
        idxf_out[grow] = (float)I1;
        if (B2 - B1 < TAU_OLD) { int p = atomicAdd(nflag, 1); flags[p] = grow; }
    }
}

__global__ __launch_bounds__(256)
void fix_old_kernel(const float* __restrict__ ze, const float* __restrict__ cb,
                    const float* __restrict__ c2, const float* __restrict__ x2,
                    const int* __restrict__ nflag, const int* __restrict__ flags,
                    int* __restrict__ idx_out, float* __restrict__ idxf_out) {
    __shared__ __align__(16) float sx[D];
    __shared__ float sbest[256];
    __shared__ int   sidx[256];
    const int tid = threadIdx.x;
    const int n   = nflag[0];
    for (int f = blockIdx.x; f < n; f += gridDim.x) {
        __syncthreads();
        const int row = flags[f];
        sx[tid] = ze[(size_t)row * D + tid];
        const float x2r = x2[row];
        __syncthreads();
        const float4* sx4 = reinterpret_cast<const float4*>(sx);
        float best = 3.4e38f; int bi = K;
        for (int k = tid; k < K; k += 256) {
            const float4* cbr = reinterpret_cast<const float4*>(&cb[(size_t)k * D]);
            double dot = 0.0;
            #pragma unroll 8
            for (int d4 = 0; d4 < D / 4; ++d4) {
                float4 c = cbr[d4]; float4 x = sx4[d4];
                dot = fma((double)x.x, (double)c.x, dot);
                dot = fma((double)x.y, (double)c.y, dot);
                dot = fma((double)x.z, (double)c.z, dot);
                dot = fma((double)x.w, (double)c.w, dot);
            }
            float P  = (float)dot;
            float t3 = __fadd_rn(x2r, __fmul_rn(-2.0f, P));
            float t4 = __fadd_rn(t3, c2[k]);
            if (t4 < best || (t4 == best && k < bi)) { best = t4; bi = k; }
        }
        sbest[tid] = best; sidx[tid] = bi;
        __syncthreads();
        for (int o = 128; o; o >>= 1) {
            if (tid < o) {
                if (sbest[tid + o] < sbest[tid] ||
                    (sbest[tid + o] == sbest[tid] && sidx[tid + o] < sidx[tid])) {
                    sbest[tid] = sbest[tid + o]; sidx[tid] = sidx[tid + o];
                }
            }
            __syncthreads();
        }
        if (tid == 0) { idx_out[row] = sidx[0]; idxf_out[row] = (float)sidx[0]; }
    }
}

// ---------------------------------------------------------------------------
// gather z_q = cb[idx] + loss reduction (deterministic two-stage)
// ---------------------------------------------------------------------------
__global__ __launch_bounds__(256)
void gather_loss_kernel(const float* __restrict__ ze, const float* __restrict__ cb,
                        const int* __restrict__ idx, float* __restrict__ zq,
                        float* __restrict__ partial) {
    const int tid  = threadIdx.x;
    const int w    = tid >> 6;
    const int lane = tid & 63;
    const int n    = blockIdx.x * 4 + w;
    const int k    = idx[n];
    float4 q = *reinterpret_cast<const float4*>(&cb[(size_t)k * D + lane * 4]);
    float4 z = *reinterpret_cast<const float4*>(&ze[(size_t)n * D + lane * 4]);
    *reinterpret_cast<float4*>(&zq[(size_t)n * D + lane * 4]) = q;
    float dx = z.x - q.x, dy = z.y - q.y, dz = z.z - q.z, dw = z.w - q.w;
    float s = dx * dx + dy * dy + dz * dz + dw * dw;
    #pragma unroll
    for (int o = 32; o; o >>= 1) s += __shfl_down(s, o);
    __shared__ float ws4[4];
    if (lane == 0) ws4[w] = s;
    __syncthreads();
    if (tid == 0) partial[blockIdx.x] = ws4[0] + ws4[1] + ws4[2] + ws4[3];
}

__global__ __launch_bounds__(256)
void final_loss_kernel(const float* __restrict__ partial, float* __restrict__ out) {
    __shared__ float sm[256];
    const int tid = threadIdx.x;
    float s = 0.0f;
    for (int i = tid; i < 8192; i += 256) s += partial[i];
    sm[tid] = s;
    __syncthreads();
    #pragma unroll
    for (int o = 128; o; o >>= 1) {
        if (tid < o) sm[tid] += sm[tid + o];
        __syncthreads();
    }
    if (tid == 0)
        out[0] = sm[0] * (1.0f + BETA) / (float)(NROWS * D);
}

// ---------------------------------------------------------------------------
extern "C" void kernel_launch(void* const* d_in, const int* in_sizes, int n_in,
                              void* d_out, int out_size, void* d_ws, size_t ws_size,
                              hipStream_t stream) {
    const float* ze = (const float*)d_in[0];
    const float* cb = (const float*)d_in[1];

    float* out  = (float*)d_out;
    float* zq   = out;
    float* idxf = out + (size_t)NROWS * D;
    float* loss = out + (size_t)NROWS * D + NROWS;

    char* ws = (char*)d_ws;
    float*  c2      = (float*) (ws);
    float*  x2      = (float*) (ws + 32768);
    int*    idx     = (int*)   (ws + 163840);
    float*  partial = (float*) (ws + 294912);
    int*    nflag   = (int*)   (ws + 327680);
    int*    flags   = (int*)   (ws + 327696);        // ends 458768
    float2* tops    = (float2*)(ws + 458768);        // KSP=2: 512 KB (slot 1 MB)
    int*    topi    = (int*)   (ws + 1507344);       // 256 KB (slot 512 KB)
    unsigned short* cbp = (unsigned short*)(ws + 2031632);   // 4.2 MB -> 6225936
    float*  scr_s   = (float*) (ws + 9633808);
    const size_t scr_base = 9633808;

    const size_t need_min = scr_base + (size_t)2048 * 4096;
    const bool newpath = ws_size >= need_min;
    int cap = 0;
    int* scr_i = nullptr;
    if (newpath) {
        size_t avail = (ws_size - scr_base) / 4096;
        cap = (int)(avail > 8192 ? 8192 : avail);
        scr_i = (int*)(ws + scr_base + (size_t)cap * 2048);
    }

    hipMemsetAsync(nflag, 0, sizeof(int), stream);
    hipLaunchKernelGGL(np_sumsq_kernel, dim3(K / 4), dim3(256), 0, stream, cb, c2, K);

    if (newpath) {
        hipLaunchKernelGGL(pack_cb_kernel,     dim3(256), dim3(256), 0, stream, cb, cbp);
        hipLaunchKernelGGL(mfma_argmin_kernel, dim3((NROWS / 256) * KSP), dim3(512), 0, stream,
                           ze, cbp, c2, tops, topi);
        hipLaunchKernelGGL(ksplit_merge_kernel, dim3(NROWS / 256), dim3(256), 0, stream,
                           tops, topi, idx, idxf, nflag, flags, TAU_NEW);
        hipLaunchKernelGGL(np_sumsq_flagged_kernel, dim3(256), dim3(64), 0, stream,
                           ze, nflag, flags, x2, cap);
        hipLaunchKernelGGL(fix1_kernel, dim3(8192), dim3(256), 0, stream,
                           ze, cb, c2, x2, nflag, flags, scr_s, scr_i, cap);
        hipLaunchKernelGGL(fix2_kernel, dim3(128), dim3(256), 0, stream,
                           nflag, flags, scr_s, scr_i, idx, idxf, cap);
    } else {
        hipLaunchKernelGGL(argmin_fp32_kernel, dim3(NROWS / 128), dim3(512), 0, stream,
                           ze, cb, c2, idx, idxf, nflag, flags);
        hipLaunchKernelGGL(np_sumsq_flagged_kernel, dim3(128), dim3(64), 0, stream,
                           ze, nflag, flags, x2, NROWS);
        hipLaunchKernelGGL(fix_old_kernel, dim3(256), dim3(256), 0, stream,
                           ze, cb, c2, x2, nflag, flags, idx, idxf);
    }

    hipLaunchKernelGGL(gather_loss_kernel, dim3(NROWS / 4), dim3(256), 0, stream,
                       ze, cb, idx, zq, partial);
    hipLaunchKernelGGL(final_loss_kernel, dim3(1), dim3(256), 0, stream,
                       partial, loss);
}

// Round 19
// 426.371 us; speedup vs baseline: 1.3639x; 1.3639x over previous
//
#include <hip/hip_runtime.h>

#define D     256
#define K     8192
#define NROWS 32768      // B*T
#define BETA  0.025f
#define TAU_NEW 2e-3f    // fp16 single-product margin (score err sigma ~2e-4)
#define TAU_OLD 2e-4f    // fp32 fallback path margin
#define RB    8          // fix1: rows per batch
#define KSP   4          // k-split ways

typedef _Float16 f16x8 __attribute__((ext_vector_type(8)));
typedef unsigned short ushort8v __attribute__((ext_vector_type(8)));
typedef float f32x16 __attribute__((ext_vector_type(16)));

#define MFMAH(a,b,c) __builtin_amdgcn_mfma_f32_32x32x16_f16(a,b,c,0,0,0)

// ---------------------------------------------------------------------------
// numpy-exact row sum-of-squares (pairwise_sum emulation, n=256); full rows
// ---------------------------------------------------------------------------
__global__ __launch_bounds__(256)
void np_sumsq_kernel(const float* __restrict__ src, float* __restrict__ dst,
                     int nrows) {
    const int tid  = threadIdx.x;
    const int w    = tid >> 6;
    const int lane = tid & 63;
    const int row  = blockIdx.x * 4 + w;
    if (row >= nrows) return;
    const float* a = src + (size_t)row * D;
    float r = 0.0f;
    if (lane < 16) {
        const float* h = a + (lane >> 3) * 128;
        const int j = lane & 7;
        float v = h[j];
        r = __fmul_rn(v, v);
        #pragma unroll
        for (int i = 8; i < 128; i += 8) {
            float u = h[i + j];
            r = __fadd_rn(r, __fmul_rn(u, u));
        }
    }
    float rr[16];
    #pragma unroll
    for (int t = 0; t < 16; ++t) rr[t] = __shfl(r, t, 64);
    if (lane == 0) {
        float h0 = __fadd_rn(__fadd_rn(__fadd_rn(rr[0], rr[1]), __fadd_rn(rr[2], rr[3])),
                             __fadd_rn(__fadd_rn(rr[4], rr[5]), __fadd_rn(rr[6], rr[7])));
        float h1 = __fadd_rn(__fadd_rn(__fadd_rn(rr[8], rr[9]), __fadd_rn(rr[10], rr[11])),
                             __fadd_rn(__fadd_rn(rr[12], rr[13]), __fadd_rn(rr[14], rr[15])));
        dst[row] = __fadd_rn(h0, h1);
    }
}

// Same, but only for flagged rows (x2 is needed only in the exact fixup).
__global__ __launch_bounds__(64)
void np_sumsq_flagged_kernel(const float* __restrict__ ze,
                             const int* __restrict__ nflag,
                             const int* __restrict__ flags,
                             float* __restrict__ x2, int cap) {
    const int lane = threadIdx.x;
    const int nf   = min(nflag[0], cap);
    for (int f = blockIdx.x; f < nf; f += gridDim.x) {
        const int row = flags[f];
        const float* a = ze + (size_t)row * D;
        float r = 0.0f;
        if (lane < 16) {
            const float* h = a + (lane >> 3) * 128;
            const int j = lane & 7;
            float v = h[j];
            r = __fmul_rn(v, v);
            #pragma unroll
            for (int i = 8; i < 128; i += 8) {
                float u = h[i + j];
                r = __fadd_rn(r, __fmul_rn(u, u));
            }
        }
        float rr[16];
        #pragma unroll
        for (int t = 0; t < 16; ++t) rr[t] = __shfl(r, t, 64);
        if (lane == 0) {
            float h0 = __fadd_rn(__fadd_rn(__fadd_rn(rr[0], rr[1]), __fadd_rn(rr[2], rr[3])),
                                 __fadd_rn(__fadd_rn(rr[4], rr[5]), __fadd_rn(rr[6], rr[7])));
            float h1 = __fadd_rn(__fadd_rn(__fadd_rn(rr[8], rr[9]), __fadd_rn(rr[10], rr[11])),
                                 __fadd_rn(__fadd_rn(rr[12], rr[13]), __fadd_rn(rr[14], rr[15])));
            x2[row] = __fadd_rn(h0, h1);
        }
    }
}

// ---------------------------------------------------------------------------
// Pack codebook into 32x32x16 f16 MFMA A-fragment order (single split).
// ushort offset = ((t*16 + c)*64 + l)*8 + j
// value = fp16( cb[t*32 + (l&31)][c*16 + 8*(l>>5) + j] )
// (k-slot map k = 8*(l>>5)+j identical for A and B -> k-permutation cancels.)
// ---------------------------------------------------------------------------
__global__ __launch_bounds__(256)
void pack_cb_kernel(const float* __restrict__ cb, unsigned short* __restrict__ cbp) {
    const int t  = blockIdx.x;          // 256 tiles of 32 codes
    const int l  = threadIdx.x & 63;
    const int cq = threadIdx.x >> 6;
    const int row = t * 32 + (l & 31);
    const int db  = 8 * (l >> 5);
    #pragma unroll
    for (int ci = 0; ci < 4; ++ci) {
        const int c  = cq * 4 + ci;
        const int d0 = c * 16 + db;
        float4 v0 = *reinterpret_cast<const float4*>(&cb[(size_t)row * D + d0]);
        float4 v1 = *reinterpret_cast<const float4*>(&cb[(size_t)row * D + d0 + 4]);
        float xv[8] = {v0.x, v0.y, v0.z, v0.w, v1.x, v1.y, v1.z, v1.w};
        f16x8 hv;
        #pragma unroll
        for (int j = 0; j < 8; ++j) hv[j] = (_Float16)xv[j];
        *reinterpret_cast<f16x8*>(cbp + (((size_t)t * 16 + c) * 64 + l) * 8) = hv;
    }
}

// ---------------------------------------------------------------------------
// MFMA distance GEMM + per-row top-2, fp16 single-product, 32x32x16.
// NO LDS, NO BARRIERS: A-fragments loaded directly from global (coalesced);
// pure function of const inputs -> replay-deterministic by construction.
// ROUND-19: fix the REMATERIALIZATION bug. R15-R18 counters showed
// VGPR_Count 72-80 vs a declared demand of ~110 (Bf=64 + acc + loads):
// the allocator, targeting max occupancy, sank the Bf build (ze loads +
// fp16 converts) INTO the 128-tile loop — 32 L3-latency loads + ~200 VALU
// per tile on the critical path. Fixes:
//  - __launch_bounds__(256, 4): 4 waves/EU min -> 128-VGPR budget.
//  - single MFMA accumulator chain (acc 32->16): demand ~105 < 128, so Bf
//    stays register-resident (no remat, no spill).
//  - KSP=4, grid 1024 -> 4 blocks/CU, 16 waves/CU of real TLP.
// ---------------------------------------------------------------------------
__global__ __launch_bounds__(256, 4)
void mfma_argmin_kernel(const float* __restrict__ ze,
                        const unsigned short* __restrict__ cbp,
                        const float* __restrict__ c2,
                        float2* __restrict__ tops, int* __restrict__ topi) {
    const int tid = threadIdx.x;
    const int l   = tid & 63;
    const int w   = tid >> 6;                   // 0..3
    const int ks  = blockIdx.x & (KSP - 1);
    const int nb  = blockIdx.x >> 2;            // log2(KSP)
    const int n   = nb * 128 + w * 32 + (l & 31);
    const int h   = l >> 5;

    // ---- z rows -> fp16 B fragments, register-resident (64 VGPR)
    f16x8 Bf[16];
    {
        const float* zr = ze + (size_t)n * D + 8 * h;
        #pragma unroll
        for (int c = 0; c < 16; ++c) {
            float4 v0 = *reinterpret_cast<const float4*>(zr + c * 16);
            float4 v1 = *reinterpret_cast<const float4*>(zr + c * 16 + 4);
            float xv[8] = {v0.x, v0.y, v0.z, v0.w, v1.x, v1.y, v1.z, v1.w};
            f16x8 hv;
            #pragma unroll
            for (int j = 0; j < 8; ++j) hv[j] = (_Float16)xv[j];
            Bf[c] = hv;
        }
    }

    const int NT = 256 / KSP;                   // tiles per block (64)
    const int t0 = ks * NT;
    const uint4* gsrc = reinterpret_cast<const uint4*>(cbp);  // tile = 1024 uint4

    float b1 = 3.4e38f, b2 = 3.4e38f;
    int   i1 = 0;

    for (int ti = 0; ti < NT; ++ti) {
        const int t = t0 + ti;
        const uint4* ab = gsrc + (size_t)t * 1024 + l;   // per-lane base

        f32x16 a0;        // single accumulator chain (16 VGPR)
        #pragma unroll
        for (int i = 0; i < 16; ++i) a0[i] = 0.0f;
        #pragma unroll
        for (int c = 0; c < 16; ++c) {
            uint4 r0 = ab[c * 64];
            a0 = MFMAH(__builtin_bit_cast(f16x8, r0), Bf[c], a0);
        }
        // epilogue: scores + running top-2 (codes ascend in processing order)
        // D mapping (m74/m101): col=l&31 (z-row), row=(reg&3)+8*(reg>>2)+4*h
        const float* c2t = c2 + t * 32 + 4 * h;
        const int base = t * 32 + 4 * h;
        #pragma unroll
        for (int g = 0; g < 4; ++g) {
            float4 cv = *reinterpret_cast<const float4*>(c2t + 8 * g);
            #pragma unroll
            for (int q = 0; q < 4; ++q) {
                const int reg = g * 4 + q;
                float dot = a0[reg];
                float cc  = (q == 0) ? cv.x : (q == 1) ? cv.y : (q == 2) ? cv.z : cv.w;
                float s   = fmaf(-2.0f, dot, cc);
                int code  = base + 8 * g + q;
                bool lt = s < b1;
                b2 = fminf(b2, lt ? b1 : s);
                i1 = lt ? code : i1;
                b1 = lt ? s : b1;
            }
        }
    }

    // merge lane l <-> l^32 (same row n)
    float ob1 = __shfl_xor(b1, 32);
    float ob2 = __shfl_xor(b2, 32);
    int   oi1 = __shfl_xor(i1, 32);
    bool take = (ob1 < b1) || (ob1 == b1 && oi1 < i1);
    float nb2 = fminf(fmaxf(b1, ob1), fminf(b2, ob2));
    float nb1 = take ? ob1 : b1;
    int   ni1 = take ? oi1 : i1;
    if (l < 32) {
        tops[(size_t)n * KSP + ks] = make_float2(nb1, nb2);
        topi[(size_t)n * KSP + ks] = ni1;
    }
}

// ---------------------------------------------------------------------------
// Merge the KSP k-split top-2 entries per row; flag near-ties.
// ks ascending = code ranges ascending; strict '<' + index tie-break keeps
// np.argmin lowest-index semantics.
// ---------------------------------------------------------------------------
__global__ __launch_bounds__(256)
void ksplit_merge_kernel(const float2* __restrict__ tops, const int* __restrict__ topi,
                         int* __restrict__ idx_out, float* __restrict__ idxf_out,
                         int* __restrict__ nflag, int* __restrict__ flags, float tau) {
    const int n = blockIdx.x * 256 + threadIdx.x;
    float2 e0 = tops[(size_t)n * KSP + 0];
    float b1 = e0.x, b2 = e0.y;
    int   bi = topi[(size_t)n * KSP + 0];
    #pragma unroll
    for (int j = 1; j < KSP; ++j) {
        float2 ej = tops[(size_t)n * KSP + j];
        int    ij = topi[(size_t)n * KSP + j];
        bool take = (ej.x < b1) || (ej.x == b1 && ij < bi);
        b2 = fminf(fminf(b2, ej.y), take ? b1 : ej.x);
        b1 = take ? ej.x : b1;
        bi = take ? ij   : bi;
    }
    idx_out[n]  = bi;
    idxf_out[n] = (float)bi;
    if (b2 - b1 < tau) {
        int p = atomicAdd(nflag, 1);
        flags[p] = n;
    }
}

// ---------------------------------------------------------------------------
// Inverted-loop exact fixup, 16 row-stripes, 8-row batching (round-13 body,
// audited: coverage 512 cbblk x 16 stripes covers every (f,cbblk); writes
// scr[f*512+cbblk] disjoint; order-independent under flag permutation).
// ---------------------------------------------------------------------------
__global__ __launch_bounds__(256)
void fix1_kernel(const float* __restrict__ ze, const float* __restrict__ cb,
                 const float* __restrict__ c2, const float* __restrict__ x2,
                 const int* __restrict__ nflag, const int* __restrict__ flags,
                 float* __restrict__ scr_s, int* __restrict__ scr_i, int cap) {
    __shared__ float sz[RB][D];        // 8 KB
    __shared__ float sbest[RB][16];
    const int tid     = threadIdx.x;
    const int cl      = tid >> 4;
    const int dt      = tid & 15;
    const int cbblk   = blockIdx.x & 511;
    const int stripe  = blockIdx.x >> 9;
    const int nstripe = gridDim.x >> 9;    // 16
    const int code    = cbblk * 16 + cl;
    const int nf      = min(nflag[0], cap);
    if (nf == 0) return;
    const int perStripe = (nf - stripe + nstripe - 1) / nstripe;
    if (perStripe <= 0) return;
    // hoist this block's cb slice into fp64 registers (once per block)
    double cbr[16];
    {
        const float* crp = cb + (size_t)code * D + dt;
        #pragma unroll
        for (int j = 0; j < 16; ++j) cbr[j] = (double)crp[16 * j];
    }
    const float cc = c2[code];
    for (int it = 0; it < perStripe; it += RB) {
        __syncthreads();                       // prev batch's scan done
        #pragma unroll
        for (int r = 0; r < RB; ++r) {
            if (it + r < perStripe) {
                const int row = flags[stripe + nstripe * (it + r)];
                sz[r][tid] = ze[(size_t)row * D + tid];
            }
        }
        __syncthreads();                       // sz visible
        #pragma unroll
        for (int r = 0; r < RB; ++r) {
            if (it + r < perStripe) {
                double dot = 0.0;
                #pragma unroll
                for (int j = 0; j < 16; ++j)
                    dot = fma((double)sz[r][dt + 16 * j], cbr[j], dot);
                #pragma unroll
                for (int o = 1; o < 16; o <<= 1)
                    dot += __shfl_xor(dot, o);
                if (dt == 0) {
                    const int f = stripe + nstripe * (it + r);
                    float P  = (float)dot;
                    float t3 = __fadd_rn(x2[flags[f]], __fmul_rn(-2.0f, P));
                    sbest[r][cl] = __fadd_rn(t3, cc);
                }
            }
        }
        __syncthreads();                       // sbest visible
        if (tid < RB && it + tid < perStripe) {
            const int f = stripe + nstripe * (it + tid);
            float bs = sbest[tid][0]; int bc = 0;
            #pragma unroll
            for (int c = 1; c < 16; ++c)
                if (sbest[tid][c] < bs) { bs = sbest[tid][c]; bc = c; }
            scr_s[(size_t)f * 512 + cbblk] = bs;
            scr_i[(size_t)f * 512 + cbblk] = cbblk * 16 + bc;
        }
    }
}

__global__ __launch_bounds__(256)
void fix2_kernel(const int* __restrict__ nflag, const int* __restrict__ flags,
                 const float* __restrict__ scr_s, const int* __restrict__ scr_i,
                 int* __restrict__ idx_out, float* __restrict__ idxf_out, int cap) {
    __shared__ float ss[256];
    __shared__ int   si[256];
    const int tid = threadIdx.x;
    const int nf  = min(nflag[0], cap);
    for (int f = blockIdx.x; f < nf; f += gridDim.x) {
        float s0 = scr_s[(size_t)f * 512 + tid];
        int   j0 = scr_i[(size_t)f * 512 + tid];
        float s1 = scr_s[(size_t)f * 512 + 256 + tid];
        int   j1 = scr_i[(size_t)f * 512 + 256 + tid];
        bool take = (s1 < s0) || (s1 == s0 && j1 < j0);
        ss[tid] = take ? s1 : s0;
        si[tid] = take ? j1 : j0;
        __syncthreads();
        for (int o = 128; o; o >>= 1) {
            if (tid < o) {
                if (ss[tid + o] < ss[tid] ||
                    (ss[tid + o] == ss[tid] && si[tid + o] < si[tid])) {
                    ss[tid] = ss[tid + o]; si[tid] = si[tid + o];
                }
            }
            __syncthreads();
        }
        if (tid == 0) {
            const int row = flags[f];
            idx_out[row]  = si[0];
            idxf_out[row] = (float)si[0];
        }
        __syncthreads();
    }
}

// ---------------------------------------------------------------------------
// FALLBACK (round-3 verified): fp32 vector GEMM + top-2, fp64 fixup.
// ---------------------------------------------------------------------------
__global__ __launch_bounds__(512)
void argmin_fp32_kernel(const float* __restrict__ ze, const float* __restrict__ cb,
                        const float* __restrict__ c2,
                        int* __restrict__ idx_out, float* __restrict__ idxf_out,
                        int* __restrict__ nflag, int* __restrict__ flags) {
    __shared__ float smem[12672];
    float* a_s = smem;
    float* b_s = smem + 32 * 128;
    const int tid  = threadIdx.x;
    const int tx   = tid & 31;
    const int ty   = tid >> 5;
    const int row0 = blockIdx.x * 128;
    float b1[8], b2[8];
    int   i1[8];
    #pragma unroll
    for (int r = 0; r < 8; ++r) { b1[r] = 3.4e38f; b2[r] = 3.4e38f; i1[r] = 0; }
    for (int kt = 0; kt < K; kt += 256) {
        float acc[8][8];
        #pragma unroll
        for (int r = 0; r < 8; ++r)
            #pragma unroll
            for (int c = 0; c < 8; ++c) acc[r][c] = 0.0f;
        for (int dc = 0; dc < D; dc += 32) {
            __syncthreads();
            #pragma unroll
            for (int j = 0; j < 2; ++j) {
                int p = tid + j * 512, ar = p >> 3, ad = (p & 7) << 2;
                float4 v = *reinterpret_cast<const float4*>(&ze[(size_t)(row0 + ar) * D + dc + ad]);
                a_s[(ad + 0) * 128 + ar] = v.x; a_s[(ad + 1) * 128 + ar] = v.y;
                a_s[(ad + 2) * 128 + ar] = v.z; a_s[(ad + 3) * 128 + ar] = v.w;
            }
            #pragma unroll
            for (int j = 0; j < 4; ++j) {
                int p = tid + j * 512, br = p >> 3, bd = (p & 7) << 2;
                float4 v = *reinterpret_cast<const float4*>(&cb[(size_t)(kt + br) * D + dc + bd]);
                b_s[(bd + 0) * 256 + br] = v.x; b_s[(bd + 1) * 256 + br] = v.y;
                b_s[(bd + 2) * 256 + br] = v.z; b_s[(bd + 3) * 256 + br] = v.w;
            }
            __syncthreads();
            #pragma unroll 4
            for (int d = 0; d < 32; ++d) {
                float4 a0  = *reinterpret_cast<const float4*>(&a_s[d * 128 + ty * 4]);
                float4 a1  = *reinterpret_cast<const float4*>(&a_s[d * 128 + 64 + ty * 4]);
                float4 b0  = *reinterpret_cast<const float4*>(&b_s[d * 256 + tx * 4]);
                float4 b1v = *reinterpret_cast<const float4*>(&b_s[d * 256 + 128 + tx * 4]);
                float av[8] = {a0.x, a0.y, a0.z, a0.w, a1.x, a1.y, a1.z, a1.w};
                float bv[8] = {b0.x, b0.y, b0.z, b0.w, b1v.x, b1v.y, b1v.z, b1v.w};
                #pragma unroll
                for (int r = 0; r < 8; ++r)
                    #pragma unroll
                    for (int c = 0; c < 8; ++c)
                        acc[r][c] = fmaf(av[r], bv[c], acc[r][c]);
            }
        }
        float4 cs0 = *reinterpret_cast<const float4*>(&c2[kt + tx * 4]);
        float4 cs1 = *reinterpret_cast<const float4*>(&c2[kt + 128 + tx * 4]);
        float cv[8] = {cs0.x, cs0.y, cs0.z, cs0.w, cs1.x, cs1.y, cs1.z, cs1.w};
        #pragma unroll
        for (int r = 0; r < 8; ++r)
            #pragma unroll
            for (int c = 0; c < 8; ++c) {
                int col = kt + ((c < 4) ? (tx * 4 + c) : (128 + tx * 4 + (c - 4)));
                float s = fmaf(-2.0f, acc[r][c], cv[c]);
                if (s < b1[r]) { b2[r] = b1[r]; b1[r] = s; i1[r] = col; }
                else if (s < b2[r]) { b2[r] = s; }
            }
    }
    __syncthreads();
    float* rs1 = smem;
    int*   ri  = (int*)(smem + 4224);
    float* rs2 = smem + 8448;
    #pragma unroll
    for (int r = 0; r < 8; ++r) {
        int lrow = (r >> 2) * 64 + ty * 4 + (r & 3);
        rs1[lrow * 33 + tx] = b1[r]; ri[lrow * 33 + tx] = i1[r]; rs2[lrow * 33 + tx] = b2[r];
    }
    __syncthreads();
    if (tid < 128) {
        float B1 = 3.4e38f, B2 = 3.4e38f;
        int I1 = 0;
        #pragma unroll 4
        for (int t = 0; t < 32; ++t) {
            float s1 = rs1[tid * 33 + t]; int j1 = ri[tid * 33 + t]; float s2 = rs2[tid * 33 + t];
            if (s1 < B1 || (s1 == B1 && j1 < I1)) { B2 = fminf(B2, B1); B1 = s1; I1 = j1; }
            else B2 = fminf(B2, s1);
            B2 = fminf(B2, s2);
        }
        int grow = row0 + tid;
        idx_out[grow] = I1;
        idxf_out[grow] = (float)I1;
        if (B2 - B1 < TAU_OLD) { int p = atomicAdd(nflag, 1); flags[p] = grow; }
    }
}

__global__ __launch_bounds__(256)
void fix_old_kernel(const float* __restrict__ ze, const float* __restrict__ cb,
                    const float* __restrict__ c2, const float* __restrict__ x2,
                    const int* __restrict__ nflag, const int* __restrict__ flags,
                    int* __restrict__ idx_out, float* __restrict__ idxf_out) {
    __shared__ __align__(16) float sx[D];
    __shared__ float sbest[256];
    __shared__ int   sidx[256];
    const int tid = threadIdx.x;
    const int n   = nflag[0];
    for (int f = blockIdx.x; f < n; f += gridDim.x) {
        __syncthreads();
        const int row = flags[f];
        sx[tid] = ze[(size_t)row * D + tid];
        const float x2r = x2[row];
        __syncthreads();
        const float4* sx4 = reinterpret_cast<const float4*>(sx);
        float best = 3.4e38f; int bi = K;
        for (int k = tid; k < K; k += 256) {
            const float4* cbr = reinterpret_cast<const float4*>(&cb[(size_t)k * D]);
            double dot = 0.0;
            #pragma unroll 8
            for (int d4 = 0; d4 < D / 4; ++d4) {
                float4 c = cbr[d4]; float4 x = sx4[d4];
                dot = fma((double)x.x, (double)c.x, dot);
                dot = fma((double)x.y, (double)c.y, dot);
                dot = fma((double)x.z, (double)c.z, dot);
                dot = fma((double)x.w, (double)c.w, dot);
            }
            float P  = (float)dot;
            float t3 = __fadd_rn(x2r, __fmul_rn(-2.0f, P));
            float t4 = __fadd_rn(t3, c2[k]);
            if (t4 < best || (t4 == best && k < bi)) { best = t4; bi = k; }
        }
        sbest[tid] = best; sidx[tid] = bi;
        __syncthreads();
        for (int o = 128; o; o >>= 1) {
            if (tid < o) {
                if (sbest[tid + o] < sbest[tid] ||
                    (sbest[tid + o] == sbest[tid] && sidx[tid + o] < sidx[tid])) {
                    sbest[tid] = sbest[tid + o]; sidx[tid] = sidx[tid + o];
                }
            }
            __syncthreads();
        }
        if (tid == 0) { idx_out[row] = sidx[0]; idxf_out[row] = (float)sidx[0]; }
    }
}

// ---------------------------------------------------------------------------
// gather z_q = cb[idx] + loss reduction (deterministic two-stage)
// ---------------------------------------------------------------------------
__global__ __launch_bounds__(256)
void gather_loss_kernel(const float* __restrict__ ze, const float* __restrict__ cb,
                        const int* __restrict__ idx, float* __restrict__ zq,
                        float* __restrict__ partial) {
    const int tid  = threadIdx.x;
    const int w    = tid >> 6;
    const int lane = tid & 63;
    const int n    = blockIdx.x * 4 + w;
    const int k    = idx[n];
    float4 q = *reinterpret_cast<const float4*>(&cb[(size_t)k * D + lane * 4]);
    float4 z = *reinterpret_cast<const float4*>(&ze[(size_t)n * D + lane * 4]);
    *reinterpret_cast<float4*>(&zq[(size_t)n * D + lane * 4]) = q;
    float dx = z.x - q.x, dy = z.y - q.y, dz = z.z - q.z, dw = z.w - q.w;
    float s = dx * dx + dy * dy + dz * dz + dw * dw;
    #pragma unroll
    for (int o = 32; o; o >>= 1) s += __shfl_down(s, o);
    __shared__ float ws4[4];
    if (lane == 0) ws4[w] = s;
    __syncthreads();
    if (tid == 0) partial[blockIdx.x] = ws4[0] + ws4[1] + ws4[2] + ws4[3];
}

__global__ __launch_bounds__(256)
void final_loss_kernel(const float* __restrict__ partial, float* __restrict__ out) {
    __shared__ float sm[256];
    const int tid = threadIdx.x;
    float s = 0.0f;
    for (int i = tid; i < 8192; i += 256) s += partial[i];
    sm[tid] = s;
    __syncthreads();
    #pragma unroll
    for (int o = 128; o; o >>= 1) {
        if (tid < o) sm[tid] += sm[tid + o];
        __syncthreads();
    }
    if (tid == 0)
        out[0] = sm[0] * (1.0f + BETA) / (float)(NROWS * D);
}

// ---------------------------------------------------------------------------
extern "C" void kernel_launch(void* const* d_in, const int* in_sizes, int n_in,
                              void* d_out, int out_size, void* d_ws, size_t ws_size,
                              hipStream_t stream) {
    const float* ze = (const float*)d_in[0];
    const float* cb = (const float*)d_in[1];

    float* out  = (float*)d_out;
    float* zq   = out;
    float* idxf = out + (size_t)NROWS * D;
    float* loss = out + (size_t)NROWS * D + NROWS;

    char* ws = (char*)d_ws;
    float*  c2      = (float*) (ws);
    float*  x2      = (float*) (ws + 32768);
    int*    idx     = (int*)   (ws + 163840);
    float*  partial = (float*) (ws + 294912);
    int*    nflag   = (int*)   (ws + 327680);
    int*    flags   = (int*)   (ws + 327696);        // ends 458768
    float2* tops    = (float2*)(ws + 458768);        // KSP=4: 1 MB -> 1507344
    int*    topi    = (int*)   (ws + 1507344);       // 512 KB -> 2031632
    unsigned short* cbp = (unsigned short*)(ws + 2031632);   // 4.2 MB -> 6225936
    float*  scr_s   = (float*) (ws + 9633808);
    const size_t scr_base = 9633808;

    const size_t need_min = scr_base + (size_t)2048 * 4096;
    const bool newpath = ws_size >= need_min;
    int cap = 0;
    int* scr_i = nullptr;
    if (newpath) {
        size_t avail = (ws_size - scr_base) / 4096;
        cap = (int)(avail > 8192 ? 8192 : avail);
        scr_i = (int*)(ws + scr_base + (size_t)cap * 2048);
    }

    hipMemsetAsync(nflag, 0, sizeof(int), stream);
    hipLaunchKernelGGL(np_sumsq_kernel, dim3(K / 4), dim3(256), 0, stream, cb, c2, K);

    if (newpath) {
        hipLaunchKernelGGL(pack_cb_kernel,     dim3(256), dim3(256), 0, stream, cb, cbp);
        hipLaunchKernelGGL(mfma_argmin_kernel, dim3((NROWS / 128) * KSP), dim3(256), 0, stream,
                           ze, cbp, c2, tops, topi);
        hipLaunchKernelGGL(ksplit_merge_kernel, dim3(NROWS / 256), dim3(256), 0, stream,
                           tops, topi, idx, idxf, nflag, flags, TAU_NEW);
        hipLaunchKernelGGL(np_sumsq_flagged_kernel, dim3(256), dim3(64), 0, stream,
                           ze, nflag, flags, x2, cap);
        hipLaunchKernelGGL(fix1_kernel, dim3(8192), dim3(256), 0, stream,
                           ze, cb, c2, x2, nflag, flags, scr_s, scr_i, cap);
        hipLaunchKernelGGL(fix2_kernel, dim3(128), dim3(256), 0, stream,
                           nflag, flags, scr_s, scr_i, idx, idxf, cap);
    } else {
        hipLaunchKernelGGL(argmin_fp32_kernel, dim3(NROWS / 128), dim3(512), 0, stream,
                           ze, cb, c2, idx, idxf, nflag, flags);
        hipLaunchKernelGGL(np_sumsq_flagged_kernel, dim3(128), dim3(64), 0, stream,
                           ze, nflag, flags, x2, NROWS);
        hipLaunchKernelGGL(fix_old_kernel, dim3(256), dim3(256), 0, stream,
                           ze, cb, c2, x2, nflag, flags, idx, idxf);
    }

    hipLaunchKernelGGL(gather_loss_kernel, dim3(NROWS / 4), dim3(256), 0, stream,
                       ze, cb, idx, zq, partial);
    hipLaunchKernelGGL(final_loss_kernel, dim3(1), dim3(256), 0, stream,
                       partial, loss);
}

// Round 20
// 425.752 us; speedup vs baseline: 1.3659x; 1.0015x over previous
//
#include <hip/hip_runtime.h>

#define D     256
#define K     8192
#define NROWS 32768      // B*T
#define BETA  0.025f
#define TAU_NEW 2e-3f    // fp16 single-product margin (score err sigma ~2e-4)
#define TAU_OLD 2e-4f    // fp32 fallback path margin
#define RB    8          // fix1: rows per batch
#define KSP   4          // k-split ways

typedef _Float16 f16x8 __attribute__((ext_vector_type(8)));
typedef unsigned short ushort8v __attribute__((ext_vector_type(8)));
typedef float f32x16 __attribute__((ext_vector_type(16)));

#define MFMAH(a,b,c) __builtin_amdgcn_mfma_f32_32x32x16_f16(a,b,c,0,0,0)

// ---------------------------------------------------------------------------
// numpy-exact row sum-of-squares (pairwise_sum emulation, n=256); full rows
// ---------------------------------------------------------------------------
__global__ __launch_bounds__(256)
void np_sumsq_kernel(const float* __restrict__ src, float* __restrict__ dst,
                     int nrows) {
    const int tid  = threadIdx.x;
    const int w    = tid >> 6;
    const int lane = tid & 63;
    const int row  = blockIdx.x * 4 + w;
    if (row >= nrows) return;
    const float* a = src + (size_t)row * D;
    float r = 0.0f;
    if (lane < 16) {
        const float* h = a + (lane >> 3) * 128;
        const int j = lane & 7;
        float v = h[j];
        r = __fmul_rn(v, v);
        #pragma unroll
        for (int i = 8; i < 128; i += 8) {
            float u = h[i + j];
            r = __fadd_rn(r, __fmul_rn(u, u));
        }
    }
    float rr[16];
    #pragma unroll
    for (int t = 0; t < 16; ++t) rr[t] = __shfl(r, t, 64);
    if (lane == 0) {
        float h0 = __fadd_rn(__fadd_rn(__fadd_rn(rr[0], rr[1]), __fadd_rn(rr[2], rr[3])),
                             __fadd_rn(__fadd_rn(rr[4], rr[5]), __fadd_rn(rr[6], rr[7])));
        float h1 = __fadd_rn(__fadd_rn(__fadd_rn(rr[8], rr[9]), __fadd_rn(rr[10], rr[11])),
                             __fadd_rn(__fadd_rn(rr[12], rr[13]), __fadd_rn(rr[14], rr[15])));
        dst[row] = __fadd_rn(h0, h1);
    }
}

// Same, but only for flagged rows (x2 is needed only in the exact fixup).
__global__ __launch_bounds__(64)
void np_sumsq_flagged_kernel(const float* __restrict__ ze,
                             const int* __restrict__ nflag,
                             const int* __restrict__ flags,
                             float* __restrict__ x2, int cap) {
    const int lane = threadIdx.x;
    const int nf   = min(nflag[0], cap);
    for (int f = blockIdx.x; f < nf; f += gridDim.x) {
        const int row = flags[f];
        const float* a = ze + (size_t)row * D;
        float r = 0.0f;
        if (lane < 16) {
            const float* h = a + (lane >> 3) * 128;
            const int j = lane & 7;
            float v = h[j];
            r = __fmul_rn(v, v);
            #pragma unroll
            for (int i = 8; i < 128; i += 8) {
                float u = h[i + j];
                r = __fadd_rn(r, __fmul_rn(u, u));
            }
        }
        float rr[16];
        #pragma unroll
        for (int t = 0; t < 16; ++t) rr[t] = __shfl(r, t, 64);
        if (lane == 0) {
            float h0 = __fadd_rn(__fadd_rn(__fadd_rn(rr[0], rr[1]), __fadd_rn(rr[2], rr[3])),
                                 __fadd_rn(__fadd_rn(rr[4], rr[5]), __fadd_rn(rr[6], rr[7])));
            float h1 = __fadd_rn(__fadd_rn(__fadd_rn(rr[8], rr[9]), __fadd_rn(rr[10], rr[11])),
                                 __fadd_rn(__fadd_rn(rr[12], rr[13]), __fadd_rn(rr[14], rr[15])));
            x2[row] = __fadd_rn(h0, h1);
        }
    }
}

// ---------------------------------------------------------------------------
// Pack codebook into 32x32x16 f16 MFMA A-fragment order (single split).
// ushort offset = ((t*16 + c)*64 + l)*8 + j
// value = fp16( cb[t*32 + (l&31)][c*16 + 8*(l>>5) + j] )
// (k-slot map k = 8*(l>>5)+j identical for A and B -> k-permutation cancels.)
// ---------------------------------------------------------------------------
__global__ __launch_bounds__(256)
void pack_cb_kernel(const float* __restrict__ cb, unsigned short* __restrict__ cbp) {
    const int t  = blockIdx.x;          // 256 tiles of 32 codes
    const int l  = threadIdx.x & 63;
    const int cq = threadIdx.x >> 6;
    const int row = t * 32 + (l & 31);
    const int db  = 8 * (l >> 5);
    #pragma unroll
    for (int ci = 0; ci < 4; ++ci) {
        const int c  = cq * 4 + ci;
        const int d0 = c * 16 + db;
        float4 v0 = *reinterpret_cast<const float4*>(&cb[(size_t)row * D + d0]);
        float4 v1 = *reinterpret_cast<const float4*>(&cb[(size_t)row * D + d0 + 4]);
        float xv[8] = {v0.x, v0.y, v0.z, v0.w, v1.x, v1.y, v1.z, v1.w};
        f16x8 hv;
        #pragma unroll
        for (int j = 0; j < 8; ++j) hv[j] = (_Float16)xv[j];
        *reinterpret_cast<f16x8*>(cbp + (((size_t)t * 16 + c) * 64 + l) * 8) = hv;
    }
}

// ---------------------------------------------------------------------------
// MFMA distance GEMM + per-row top-2, fp16 single-product, 32x32x16.
// NO LDS, NO BARRIERS: A-fragments loaded directly from global (coalesced);
// pure function of const inputs -> replay-deterministic by construction.
// ROUND-20: pin waves/EU EXACTLY at 4. R19's __launch_bounds__(256,4) only
// set a MINIMUM; the allocator chose 8 waves/EU (VGPR_Count=64) and still
// remats the Bf build per tile (64 regs cannot hold Bf=64 + acc=16 +
// addressing). amdgpu_waves_per_eu(4,4) pins min=max=4 -> 128-VGPR budget
// with demand ~105 -> Bf register-resident, no remat, no spill.
// ---------------------------------------------------------------------------
__global__ __launch_bounds__(256) __attribute__((amdgpu_waves_per_eu(4, 4)))
void mfma_argmin_kernel(const float* __restrict__ ze,
                        const unsigned short* __restrict__ cbp,
                        const float* __restrict__ c2,
                        float2* __restrict__ tops, int* __restrict__ topi) {
    const int tid = threadIdx.x;
    const int l   = tid & 63;
    const int w   = tid >> 6;                   // 0..3
    const int ks  = blockIdx.x & (KSP - 1);
    const int nb  = blockIdx.x >> 2;            // log2(KSP)
    const int n   = nb * 128 + w * 32 + (l & 31);
    const int h   = l >> 5;

    // ---- z rows -> fp16 B fragments, register-resident (64 VGPR)
    f16x8 Bf[16];
    {
        const float* zr = ze + (size_t)n * D + 8 * h;
        #pragma unroll
        for (int c = 0; c < 16; ++c) {
            float4 v0 = *reinterpret_cast<const float4*>(zr + c * 16);
            float4 v1 = *reinterpret_cast<const float4*>(zr + c * 16 + 4);
            float xv[8] = {v0.x, v0.y, v0.z, v0.w, v1.x, v1.y, v1.z, v1.w};
            f16x8 hv;
            #pragma unroll
            for (int j = 0; j < 8; ++j) hv[j] = (_Float16)xv[j];
            Bf[c] = hv;
        }
    }

    const int NT = 256 / KSP;                   // tiles per block (64)
    const int t0 = ks * NT;
    const uint4* gsrc = reinterpret_cast<const uint4*>(cbp);  // tile = 1024 uint4

    float b1 = 3.4e38f, b2 = 3.4e38f;
    int   i1 = 0;

    for (int ti = 0; ti < NT; ++ti) {
        const int t = t0 + ti;
        const uint4* ab = gsrc + (size_t)t * 1024 + l;   // per-lane base

        f32x16 a0;        // single accumulator chain (16 VGPR)
        #pragma unroll
        for (int i = 0; i < 16; ++i) a0[i] = 0.0f;
        #pragma unroll
        for (int c = 0; c < 16; ++c) {
            uint4 r0 = ab[c * 64];
            a0 = MFMAH(__builtin_bit_cast(f16x8, r0), Bf[c], a0);
        }
        // epilogue: scores + running top-2 (codes ascend in processing order)
        // D mapping (m74/m101): col=l&31 (z-row), row=(reg&3)+8*(reg>>2)+4*h
        const float* c2t = c2 + t * 32 + 4 * h;
        const int base = t * 32 + 4 * h;
        #pragma unroll
        for (int g = 0; g < 4; ++g) {
            float4 cv = *reinterpret_cast<const float4*>(c2t + 8 * g);
            #pragma unroll
            for (int q = 0; q < 4; ++q) {
                const int reg = g * 4 + q;
                float dot = a0[reg];
                float cc  = (q == 0) ? cv.x : (q == 1) ? cv.y : (q == 2) ? cv.z : cv.w;
                float s   = fmaf(-2.0f, dot, cc);
                int code  = base + 8 * g + q;
                bool lt = s < b1;
                b2 = fminf(b2, lt ? b1 : s);
                i1 = lt ? code : i1;
                b1 = lt ? s : b1;
            }
        }
    }

    // merge lane l <-> l^32 (same row n)
    float ob1 = __shfl_xor(b1, 32);
    float ob2 = __shfl_xor(b2, 32);
    int   oi1 = __shfl_xor(i1, 32);
    bool take = (ob1 < b1) || (ob1 == b1 && oi1 < i1);
    float nb2 = fminf(fmaxf(b1, ob1), fminf(b2, ob2));
    float nb1 = take ? ob1 : b1;
    int   ni1 = take ? oi1 : i1;
    if (l < 32) {
        tops[(size_t)n * KSP + ks] = make_float2(nb1, nb2);
        topi[(size_t)n * KSP + ks] = ni1;
    }
}

// ---------------------------------------------------------------------------
// Merge the KSP k-split top-2 entries per row; flag near-ties.
// ks ascending = code ranges ascending; strict '<' + index tie-break keeps
// np.argmin lowest-index semantics.
// ---------------------------------------------------------------------------
__global__ __launch_bounds__(256)
void ksplit_merge_kernel(const float2* __restrict__ tops, const int* __restrict__ topi,
                         int* __restrict__ idx_out, float* __restrict__ idxf_out,
                         int* __restrict__ nflag, int* __restrict__ flags, float tau) {
    const int n = blockIdx.x * 256 + threadIdx.x;
    float2 e0 = tops[(size_t)n * KSP + 0];
    float b1 = e0.x, b2 = e0.y;
    int   bi = topi[(size_t)n * KSP + 0];
    #pragma unroll
    for (int j = 1; j < KSP; ++j) {
        float2 ej = tops[(size_t)n * KSP + j];
        int    ij = topi[(size_t)n * KSP + j];
        bool take = (ej.x < b1) || (ej.x == b1 && ij < bi);
        b2 = fminf(fminf(b2, ej.y), take ? b1 : ej.x);
        b1 = take ? ej.x : b1;
        bi = take ? ij   : bi;
    }
    idx_out[n]  = bi;
    idxf_out[n] = (float)bi;
    if (b2 - b1 < tau) {
        int p = atomicAdd(nflag, 1);
        flags[p] = n;
    }
}

// ---------------------------------------------------------------------------
// Inverted-loop exact fixup, 16 row-stripes, 8-row batching (round-13 body,
// audited: coverage 512 cbblk x 16 stripes covers every (f,cbblk); writes
// scr[f*512+cbblk] disjoint; order-independent under flag permutation).
// ---------------------------------------------------------------------------
__global__ __launch_bounds__(256)
void fix1_kernel(const float* __restrict__ ze, const float* __restrict__ cb,
                 const float* __restrict__ c2, const float* __restrict__ x2,
                 const int* __restrict__ nflag, const int* __restrict__ flags,
                 float* __restrict__ scr_s, int* __restrict__ scr_i, int cap) {
    __shared__ float sz[RB][D];        // 8 KB
    __shared__ float sbest[RB][16];
    const int tid     = threadIdx.x;
    const int cl      = tid >> 4;
    const int dt      = tid & 15;
    const int cbblk   = blockIdx.x & 511;
    const int stripe  = blockIdx.x >> 9;
    const int nstripe = gridDim.x >> 9;    // 16
    const int code    = cbblk * 16 + cl;
    const int nf      = min(nflag[0], cap);
    if (nf == 0) return;
    const int perStripe = (nf - stripe + nstripe - 1) / nstripe;
    if (perStripe <= 0) return;
    // hoist this block's cb slice into fp64 registers (once per block)
    double cbr[16];
    {
        const float* crp = cb + (size_t)code * D + dt;
        #pragma unroll
        for (int j = 0; j < 16; ++j) cbr[j] = (double)crp[16 * j];
    }
    const float cc = c2[code];
    for (int it = 0; it < perStripe; it += RB) {
        __syncthreads();                       // prev batch's scan done
        #pragma unroll
        for (int r = 0; r < RB; ++r) {
            if (it + r < perStripe) {
                const int row = flags[stripe + nstripe * (it + r)];
                sz[r][tid] = ze[(size_t)row * D + tid];
            }
        }
        __syncthreads();                       // sz visible
        #pragma unroll
        for (int r = 0; r < RB; ++r) {
            if (it + r < perStripe) {
                double dot = 0.0;
                #pragma unroll
                for (int j = 0; j < 16; ++j)
                    dot = fma((double)sz[r][dt + 16 * j], cbr[j], dot);
                #pragma unroll
                for (int o = 1; o < 16; o <<= 1)
                    dot += __shfl_xor(dot, o);
                if (dt == 0) {
                    const int f = stripe + nstripe * (it + r);
                    float P  = (float)dot;
                    float t3 = __fadd_rn(x2[flags[f]], __fmul_rn(-2.0f, P));
                    sbest[r][cl] = __fadd_rn(t3, cc);
                }
            }
        }
        __syncthreads();                       // sbest visible
        if (tid < RB && it + tid < perStripe) {
            const int f = stripe + nstripe * (it + tid);
            float bs = sbest[tid][0]; int bc = 0;
            #pragma unroll
            for (int c = 1; c < 16; ++c)
                if (sbest[tid][c] < bs) { bs = sbest[tid][c]; bc = c; }
            scr_s[(size_t)f * 512 + cbblk] = bs;
            scr_i[(size_t)f * 512 + cbblk] = cbblk * 16 + bc;
        }
    }
}

__global__ __launch_bounds__(256)
void fix2_kernel(const int* __restrict__ nflag, const int* __restrict__ flags,
                 const float* __restrict__ scr_s, const int* __restrict__ scr_i,
                 int* __restrict__ idx_out, float* __restrict__ idxf_out, int cap) {
    __shared__ float ss[256];
    __shared__ int   si[256];
    const int tid = threadIdx.x;
    const int nf  = min(nflag[0], cap);
    for (int f = blockIdx.x; f < nf; f += gridDim.x) {
        float s0 = scr_s[(size_t)f * 512 + tid];
        int   j0 = scr_i[(size_t)f * 512 + tid];
        float s1 = scr_s[(size_t)f * 512 + 256 + tid];
        int   j1 = scr_i[(size_t)f * 512 + 256 + tid];
        bool take = (s1 < s0) || (s1 == s0 && j1 < j0);
        ss[tid] = take ? s1 : s0;
        si[tid] = take ? j1 : j0;
        __syncthreads();
        for (int o = 128; o; o >>= 1) {
            if (tid < o) {
                if (ss[tid + o] < ss[tid] ||
                    (ss[tid + o] == ss[tid] && si[tid + o] < si[tid])) {
                    ss[tid] = ss[tid + o]; si[tid] = si[tid + o];
                }
            }
            __syncthreads();
        }
        if (tid == 0) {
            const int row = flags[f];
            idx_out[row]  = si[0];
            idxf_out[row] = (float)si[0];
        }
        __syncthreads();
    }
}

// ---------------------------------------------------------------------------
// FALLBACK (round-3 verified): fp32 vector GEMM + top-2, fp64 fixup.
// ---------------------------------------------------------------------------
__global__ __launch_bounds__(512)
void argmin_fp32_kernel(const float* __restrict__ ze, const float* __restrict__ cb,
                        const float* __restrict__ c2,
                        int* __restrict__ idx_out, float* __restrict__ idxf_out,
                        int* __restrict__ nflag, int* __restrict__ flags) {
    __shared__ float smem[12672];
    float* a_s = smem;
    float* b_s = smem + 32 * 128;
    const int tid  = threadIdx.x;
    const int tx   = tid & 31;
    const int ty   = tid >> 5;
    const int row0 = blockIdx.x * 128;
    float b1[8], b2[8];
    int   i1[8];
    #pragma unroll
    for (int r = 0; r < 8; ++r) { b1[r] = 3.4e38f; b2[r] = 3.4e38f; i1[r] = 0; }
    for (int kt = 0; kt < K; kt += 256) {
        float acc[8][8];
        #pragma unroll
        for (int r = 0; r < 8; ++r)
            #pragma unroll
            for (int c = 0; c < 8; ++c) acc[r][c] = 0.0f;
        for (int dc = 0; dc < D; dc += 32) {
            __syncthreads();
            #pragma unroll
            for (int j = 0; j < 2; ++j) {
                int p = tid + j * 512, ar = p >> 3, ad = (p & 7) << 2;
                float4 v = *reinterpret_cast<const float4*>(&ze[(size_t)(row0 + ar) * D + dc + ad]);
                a_s[(ad + 0) * 128 + ar] = v.x; a_s[(ad + 1) * 128 + ar] = v.y;
                a_s[(ad + 2) * 128 + ar] = v.z; a_s[(ad + 3) * 128 + ar] = v.w;
            }
            #pragma unroll
            for (int j = 0; j < 4; ++j) {
                int p = tid + j * 512, br = p >> 3, bd = (p & 7) << 2;
                float4 v = *reinterpret_cast<const float4*>(&cb[(size_t)(kt + br) * D + dc + bd]);
                b_s[(bd + 0) * 256 + br] = v.x; b_s[(bd + 1) * 256 + br] = v.y;
                b_s[(bd + 2) * 256 + br] = v.z; b_s[(bd + 3) * 256 + br] = v.w;
            }
            __syncthreads();
            #pragma unroll 4
            for (int d = 0; d < 32; ++d) {
                float4 a0  = *reinterpret_cast<const float4*>(&a_s[d * 128 + ty * 4]);
                float4 a1  = *reinterpret_cast<const float4*>(&a_s[d * 128 + 64 + ty * 4]);
                float4 b0  = *reinterpret_cast<const float4*>(&b_s[d * 256 + tx * 4]);
                float4 b1v = *reinterpret_cast<const float4*>(&b_s[d * 256 + 128 + tx * 4]);
                float av[8] = {a0.x, a0.y, a0.z, a0.w, a1.x, a1.y, a1.z, a1.w};
                float bv[8] = {b0.x, b0.y, b0.z, b0.w, b1v.x, b1v.y, b1v.z, b1v.w};
                #pragma unroll
                for (int r = 0; r < 8; ++r)
                    #pragma unroll
                    for (int c = 0; c < 8; ++c)
                        acc[r][c] = fmaf(av[r], bv[c], acc[r][c]);
            }
        }
        float4 cs0 = *reinterpret_cast<const float4*>(&c2[kt + tx * 4]);
        float4 cs1 = *reinterpret_cast<const float4*>(&c2[kt + 128 + tx * 4]);
        float cv[8] = {cs0.x, cs0.y, cs0.z, cs0.w, cs1.x, cs1.y, cs1.z, cs1.w};
        #pragma unroll
        for (int r = 0; r < 8; ++r)
            #pragma unroll
            for (int c = 0; c < 8; ++c) {
                int col = kt + ((c < 4) ? (tx * 4 + c) : (128 + tx * 4 + (c - 4)));
                float s = fmaf(-2.0f, acc[r][c], cv[c]);
                if (s < b1[r]) { b2[r] = b1[r]; b1[r] = s; i1[r] = col; }
                else if (s < b2[r]) { b2[r] = s; }
            }
    }
    __syncthreads();
    float* rs1 = smem;
    int*   ri  = (int*)(smem + 4224);
    float* rs2 = smem + 8448;
    #pragma unroll
    for (int r = 0; r < 8; ++r) {
        int lrow = (r >> 2) * 64 + ty * 4 + (r & 3);
        rs1[lrow * 33 + tx] = b1[r]; ri[lrow * 33 + tx] = i1[r]; rs2[lrow * 33 + tx] = b2[r];
    }
    __syncthreads();
    if (tid < 128) {
        float B1 = 3.4e38f, B2 = 3.4e38f;
        int I1 = 0;
        #pragma unroll 4
        for (int t = 0; t < 32; ++t) {
            float s1 = rs1[tid * 33 + t]; int j1 = ri[tid * 33 + t]; float s2 = rs2[tid * 33 + t];
            if (s1 < B1 || (s1 == B1 && j1 < I1)) { B2 = fminf(B2, B1); B1 = s1; I1 = j1; }
            else B2 = fminf(B2, s1);
            B2 = fminf(B2, s2);
        }
        int grow = row0 + tid;
        idx_out[grow] = I1;
        idxf_out[grow] = (float)I1;
        if (B2 - B1 < TAU_OLD) { int p = atomicAdd(nflag, 1); flags[p] = grow; }
    }
}

__global__ __launch_bounds__(256)
void fix_old_kernel(const float* __restrict__ ze, const float* __restrict__ cb,
                    const float* __restrict__ c2, const float* __restrict__ x2,
                    const int* __restrict__ nflag, const int* __restrict__ flags,
                    int* __restrict__ idx_out, float* __restrict__ idxf_out) {
    __shared__ __align__(16) float sx[D];
    __shared__ float sbest[256];
    __shared__ int   sidx[256];
    const int tid = threadIdx.x;
    const int n   = nflag[0];
    for (int f = blockIdx.x; f < n; f += gridDim.x) {
        __syncthreads();
        const int row = flags[f];
        sx[tid] = ze[(size_t)row * D + tid];
        const float x2r = x2[row];
        __syncthreads();
        const float4* sx4 = reinterpret_cast<const float4*>(sx);
        float best = 3.4e38f; int bi = K;
        for (int k = tid; k < K; k += 256) {
            const float4* cbr = reinterpret_cast<const float4*>(&cb[(size_t)k * D]);
            double dot = 0.0;
            #pragma unroll 8
            for (int d4 = 0; d4 < D / 4; ++d4) {
                float4 c = cbr[d4]; float4 x = sx4[d4];
                dot = fma((double)x.x, (double)c.x, dot);
                dot = fma((double)x.y, (double)c.y, dot);
                dot = fma((double)x.z, (double)c.z, dot);
                dot = fma((double)x.w, (double)c.w, dot);
            }
            float P  = (float)dot;
            float t3 = __fadd_rn(x2r, __fmul_rn(-2.0f, P));
            float t4 = __fadd_rn(t3, c2[k]);
            if (t4 < best || (t4 == best && k < bi)) { best = t4; bi = k; }
        }
        sbest[tid] = best; sidx[tid] = bi;
        __syncthreads();
        for (int o = 128; o; o >>= 1) {
            if (tid < o) {
                if (sbest[tid + o] < sbest[tid] ||
                    (sbest[tid + o] == sbest[tid] && sidx[tid + o] < sidx[tid])) {
                    sbest[tid] = sbest[tid + o]; sidx[tid] = sidx[tid + o];
                }
            }
            __syncthreads();
        }
        if (tid == 0) { idx_out[row] = sidx[0]; idxf_out[row] = (float)sidx[0]; }
    }
}

// ---------------------------------------------------------------------------
// gather z_q = cb[idx] + loss reduction (deterministic two-stage)
// ---------------------------------------------------------------------------
__global__ __launch_bounds__(256)
void gather_loss_kernel(const float* __restrict__ ze, const float* __restrict__ cb,
                        const int* __restrict__ idx, float* __restrict__ zq,
                        float* __restrict__ partial) {
    const int tid  = threadIdx.x;
    const int w    = tid >> 6;
    const int lane = tid & 63;
    const int n    = blockIdx.x * 4 + w;
    const int k    = idx[n];
    float4 q = *reinterpret_cast<const float4*>(&cb[(size_t)k * D + lane * 4]);
    float4 z = *reinterpret_cast<const float4*>(&ze[(size_t)n * D + lane * 4]);
    *reinterpret_cast<float4*>(&zq[(size_t)n * D + lane * 4]) = q;
    float dx = z.x - q.x, dy = z.y - q.y, dz = z.z - q.z, dw = z.w - q.w;
    float s = dx * dx + dy * dy + dz * dz + dw * dw;
    #pragma unroll
    for (int o = 32; o; o >>= 1) s += __shfl_down(s, o);
    __shared__ float ws4[4];
    if (lane == 0) ws4[w] = s;
    __syncthreads();
    if (tid == 0) partial[blockIdx.x] = ws4[0] + ws4[1] + ws4[2] + ws4[3];
}

__global__ __launch_bounds__(256)
void final_loss_kernel(const float* __restrict__ partial, float* __restrict__ out) {
    __shared__ float sm[256];
    const int tid = threadIdx.x;
    float s = 0.0f;
    for (int i = tid; i < 8192; i += 256) s += partial[i];
    sm[tid] = s;
    __syncthreads();
    #pragma unroll
    for (int o = 128; o; o >>= 1) {
        if (tid < o) sm[tid] += sm[tid + o];
        __syncthreads();
    }
    if (tid == 0)
        out[0] = sm[0] * (1.0f + BETA) / (float)(NROWS * D);
}

// ---------------------------------------------------------------------------
extern "C" void kernel_launch(void* const* d_in, const int* in_sizes, int n_in,
                              void* d_out, int out_size, void* d_ws, size_t ws_size,
                              hipStream_t stream) {
    const float* ze = (const float*)d_in[0];
    const float* cb = (const float*)d_in[1];

    float* out  = (float*)d_out;
    float* zq   = out;
    float* idxf = out + (size_t)NROWS * D;
    float* loss = out + (size_t)NROWS * D + NROWS;

    char* ws = (char*)d_ws;
    float*  c2      = (float*) (ws);
    float*  x2      = (float*) (ws + 32768);
    int*    idx     = (int*)   (ws + 163840);
    float*  partial = (float*) (ws + 294912);
    int*    nflag   = (int*)   (ws + 327680);
    int*    flags   = (int*)   (ws + 327696);        // ends 458768
    float2* tops    = (float2*)(ws + 458768);        // KSP=4: 1 MB -> 1507344
    int*    topi    = (int*)   (ws + 1507344);       // 512 KB -> 2031632
    unsigned short* cbp = (unsigned short*)(ws + 2031632);   // 4.2 MB -> 6225936
    float*  scr_s   = (float*) (ws + 9633808);
    const size_t scr_base = 9633808;

    const size_t need_min = scr_base + (size_t)2048 * 4096;
    const bool newpath = ws_size >= need_min;
    int cap = 0;
    int* scr_i = nullptr;
    if (newpath) {
        size_t avail = (ws_size - scr_base) / 4096;
        cap = (int)(avail > 8192 ? 8192 : avail);
        scr_i = (int*)(ws + scr_base + (size_t)cap * 2048);
    }

    hipMemsetAsync(nflag, 0, sizeof(int), stream);
    hipLaunchKernelGGL(np_sumsq_kernel, dim3(K / 4), dim3(256), 0, stream, cb, c2, K);

    if (newpath) {
        hipLaunchKernelGGL(pack_cb_kernel,     dim3(256), dim3(256), 0, stream, cb, cbp);
        hipLaunchKernelGGL(mfma_argmin_kernel, dim3((NROWS / 128) * KSP), dim3(256), 0, stream,
                           ze, cbp, c2, tops, topi);
        hipLaunchKernelGGL(ksplit_merge_kernel, dim3(NROWS / 256), dim3(256), 0, stream,
                           tops, topi, idx, idxf, nflag, flags, TAU_NEW);
        hipLaunchKernelGGL(np_sumsq_flagged_kernel, dim3(256), dim3(64), 0, stream,
                           ze, nflag, flags, x2, cap);
        hipLaunchKernelGGL(fix1_kernel, dim3(8192), dim3(256), 0, stream,
                           ze, cb, c2, x2, nflag, flags, scr_s, scr_i, cap);
        hipLaunchKernelGGL(fix2_kernel, dim3(128), dim3(256), 0, stream,
                           nflag, flags, scr_s, scr_i, idx, idxf, cap);
    } else {
        hipLaunchKernelGGL(argmin_fp32_kernel, dim3(NROWS / 128), dim3(512), 0, stream,
                           ze, cb, c2, idx, idxf, nflag, flags);
        hipLaunchKernelGGL(np_sumsq_flagged_kernel, dim3(128), dim3(64), 0, stream,
                           ze, nflag, flags, x2, NROWS);
        hipLaunchKernelGGL(fix_old_kernel, dim3(256), dim3(256), 0, stream,
                           ze, cb, c2, x2, nflag, flags, idx, idxf);
    }

    hipLaunchKernelGGL(gather_loss_kernel, dim3(NROWS / 4), dim3(256), 0, stream,
                       ze, cb, idx, zq, partial);
    hipLaunchKernelGGL(final_loss_kernel, dim3(1), dim3(256), 0, stream,
                       partial, loss);
}

// Round 22
// 425.616 us; speedup vs baseline: 1.3663x; 1.0003x over previous
//
#include <hip/hip_runtime.h>

#define D     256
#define K     8192
#define NROWS 32768      // B*T
#define BETA  0.025f
#define TAU_NEW 2e-3f    // fp16 single-product margin (score err sigma ~2e-4)
#define TAU_OLD 2e-4f    // fp32 fallback path margin
#define RB    8          // fix1: rows per batch
#define KSP   4          // k-split ways

typedef _Float16 f16x8 __attribute__((ext_vector_type(8)));
typedef unsigned short ushort8v __attribute__((ext_vector_type(8)));
typedef float f32x16 __attribute__((ext_vector_type(16)));

#define MFMAH(a,b,c) __builtin_amdgcn_mfma_f32_32x32x16_f16(a,b,c,0,0,0)

// ---------------------------------------------------------------------------
// numpy-exact row sum-of-squares (pairwise_sum emulation, n=256); full rows
// ---------------------------------------------------------------------------
__global__ __launch_bounds__(256)
void np_sumsq_kernel(const float* __restrict__ src, float* __restrict__ dst,
                     int nrows) {
    const int tid  = threadIdx.x;
    const int w    = tid >> 6;
    const int lane = tid & 63;
    const int row  = blockIdx.x * 4 + w;
    if (row >= nrows) return;
    const float* a = src + (size_t)row * D;
    float r = 0.0f;
    if (lane < 16) {
        const float* h = a + (lane >> 3) * 128;
        const int j = lane & 7;
        float v = h[j];
        r = __fmul_rn(v, v);
        #pragma unroll
        for (int i = 8; i < 128; i += 8) {
            float u = h[i + j];
            r = __fadd_rn(r, __fmul_rn(u, u));
        }
    }
    float rr[16];
    #pragma unroll
    for (int t = 0; t < 16; ++t) rr[t] = __shfl(r, t, 64);
    if (lane == 0) {
        float h0 = __fadd_rn(__fadd_rn(__fadd_rn(rr[0], rr[1]), __fadd_rn(rr[2], rr[3])),
                             __fadd_rn(__fadd_rn(rr[4], rr[5]), __fadd_rn(rr[6], rr[7])));
        float h1 = __fadd_rn(__fadd_rn(__fadd_rn(rr[8], rr[9]), __fadd_rn(rr[10], rr[11])),
                             __fadd_rn(__fadd_rn(rr[12], rr[13]), __fadd_rn(rr[14], rr[15])));
        dst[row] = __fadd_rn(h0, h1);
    }
}

// Same, but only for flagged rows (x2 is needed only in the exact fixup).
__global__ __launch_bounds__(64)
void np_sumsq_flagged_kernel(const float* __restrict__ ze,
                             const int* __restrict__ nflag,
                             const int* __restrict__ flags,
                             float* __restrict__ x2, int cap) {
    const int lane = threadIdx.x;
    const int nf   = min(nflag[0], cap);
    for (int f = blockIdx.x; f < nf; f += gridDim.x) {
        const int row = flags[f];
        const float* a = ze + (size_t)row * D;
        float r = 0.0f;
        if (lane < 16) {
            const float* h = a + (lane >> 3) * 128;
            const int j = lane & 7;
            float v = h[j];
            r = __fmul_rn(v, v);
            #pragma unroll
            for (int i = 8; i < 128; i += 8) {
                float u = h[i + j];
                r = __fadd_rn(r, __fmul_rn(u, u));
            }
        }
        float rr[16];
        #pragma unroll
        for (int t = 0; t < 16; ++t) rr[t] = __shfl(r, t, 64);
        if (lane == 0) {
            float h0 = __fadd_rn(__fadd_rn(__fadd_rn(rr[0], rr[1]), __fadd_rn(rr[2], rr[3])),
                                 __fadd_rn(__fadd_rn(rr[4], rr[5]), __fadd_rn(rr[6], rr[7])));
            float h1 = __fadd_rn(__fadd_rn(__fadd_rn(rr[8], rr[9]), __fadd_rn(rr[10], rr[11])),
                                 __fadd_rn(__fadd_rn(rr[12], rr[13]), __fadd_rn(rr[14], rr[15])));
            x2[row] = __fadd_rn(h0, h1);
        }
    }
}

// ---------------------------------------------------------------------------
// Pack codebook into 32x32x16 f16 MFMA A-fragment order (single split).
// ushort offset = ((t*16 + c)*64 + l)*8 + j
// value = fp16( cb[t*32 + (l&31)][c*16 + 8*(l>>5) + j] )
// (k-slot map k = 8*(l>>5)+j identical for A and B -> k-permutation cancels.)
// ---------------------------------------------------------------------------
__global__ __launch_bounds__(256)
void pack_cb_kernel(const float* __restrict__ cb, unsigned short* __restrict__ cbp) {
    const int t  = blockIdx.x;          // 256 tiles of 32 codes
    const int l  = threadIdx.x & 63;
    const int cq = threadIdx.x >> 6;
    const int row = t * 32 + (l & 31);
    const int db  = 8 * (l >> 5);
    #pragma unroll
    for (int ci = 0; ci < 4; ++ci) {
        const int c  = cq * 4 + ci;
        const int d0 = c * 16 + db;
        float4 v0 = *reinterpret_cast<const float4*>(&cb[(size_t)row * D + d0]);
        float4 v1 = *reinterpret_cast<const float4*>(&cb[(size_t)row * D + d0 + 4]);
        float xv[8] = {v0.x, v0.y, v0.z, v0.w, v1.x, v1.y, v1.z, v1.w};
        f16x8 hv;
        #pragma unroll
        for (int j = 0; j < 8; ++j) hv[j] = (_Float16)xv[j];
        *reinterpret_cast<f16x8*>(cbp + (((size_t)t * 16 + c) * 64 + l) * 8) = hv;
    }
}

// ---------------------------------------------------------------------------
// MFMA distance GEMM + per-row top-2, fp16 single-product, 32x32x16.
// NO LDS, NO BARRIERS: A-fragments loaded directly from global (coalesced);
// pure function of const inputs -> replay-deterministic by construction.
// ROUND-22: same remat-kill as R21 but with SCALAR asm operands (R21's
// 128-bit "+v"(uint4) hit "tied indirect register inputs" — unsupported).
// Per-32-bit "+v" touches make all 64 fragment registers opaque -> remat
// illegal -> Bf register-resident. waves_per_eu(4,4) keeps the 128-VGPR
// budget; demand ~105 fits, no spill.
// ---------------------------------------------------------------------------
__global__ __launch_bounds__(256) __attribute__((amdgpu_waves_per_eu(4, 4)))
void mfma_argmin_kernel(const float* __restrict__ ze,
                        const unsigned short* __restrict__ cbp,
                        const float* __restrict__ c2,
                        float2* __restrict__ tops, int* __restrict__ topi) {
    const int tid = threadIdx.x;
    const int l   = tid & 63;
    const int w   = tid >> 6;                   // 0..3
    const int ks  = blockIdx.x & (KSP - 1);
    const int nb  = blockIdx.x >> 2;            // log2(KSP)
    const int n   = nb * 128 + w * 32 + (l & 31);
    const int h   = l >> 5;

    // ---- z rows -> fp16 B fragments, register-resident (64 VGPR)
    uint4 Bu[16];
    {
        const float* zr = ze + (size_t)n * D + 8 * h;
        #pragma unroll
        for (int c = 0; c < 16; ++c) {
            float4 v0 = *reinterpret_cast<const float4*>(zr + c * 16);
            float4 v1 = *reinterpret_cast<const float4*>(zr + c * 16 + 4);
            float xv[8] = {v0.x, v0.y, v0.z, v0.w, v1.x, v1.y, v1.z, v1.w};
            f16x8 hv;
            #pragma unroll
            for (int j = 0; j < 8; ++j) hv[j] = (_Float16)xv[j];
            Bu[c] = __builtin_bit_cast(uint4, hv);
        }
    }
    // opaque-touch each fragment component (32-bit tied operands are
    // supported): compiler cannot rematerialize the Bf build past this.
    #pragma unroll
    for (int c = 0; c < 16; ++c)
        asm volatile("" : "+v"(Bu[c].x), "+v"(Bu[c].y),
                          "+v"(Bu[c].z), "+v"(Bu[c].w));

    const int NT = 256 / KSP;                   // tiles per block (64)
    const int t0 = ks * NT;
    const uint4* gsrc = reinterpret_cast<const uint4*>(cbp);  // tile = 1024 uint4

    float b1 = 3.4e38f, b2 = 3.4e38f;
    int   i1 = 0;

    for (int ti = 0; ti < NT; ++ti) {
        const int t = t0 + ti;
        const uint4* ab = gsrc + (size_t)t * 1024 + l;   // per-lane base

        f32x16 a0;        // single accumulator chain (16 VGPR)
        #pragma unroll
        for (int i = 0; i < 16; ++i) a0[i] = 0.0f;
        #pragma unroll
        for (int c = 0; c < 16; ++c) {
            uint4 r0 = ab[c * 64];
            a0 = MFMAH(__builtin_bit_cast(f16x8, r0),
                       __builtin_bit_cast(f16x8, Bu[c]), a0);
        }
        // epilogue: scores + running top-2 (codes ascend in processing order)
        // D mapping (m74/m101): col=l&31 (z-row), row=(reg&3)+8*(reg>>2)+4*h
        const float* c2t = c2 + t * 32 + 4 * h;
        const int base = t * 32 + 4 * h;
        #pragma unroll
        for (int g = 0; g < 4; ++g) {
            float4 cv = *reinterpret_cast<const float4*>(c2t + 8 * g);
            #pragma unroll
            for (int q = 0; q < 4; ++q) {
                const int reg = g * 4 + q;
                float dot = a0[reg];
                float cc  = (q == 0) ? cv.x : (q == 1) ? cv.y : (q == 2) ? cv.z : cv.w;
                float s   = fmaf(-2.0f, dot, cc);
                int code  = base + 8 * g + q;
                bool lt = s < b1;
                b2 = fminf(b2, lt ? b1 : s);
                i1 = lt ? code : i1;
                b1 = lt ? s : b1;
            }
        }
    }

    // merge lane l <-> l^32 (same row n)
    float ob1 = __shfl_xor(b1, 32);
    float ob2 = __shfl_xor(b2, 32);
    int   oi1 = __shfl_xor(i1, 32);
    bool take = (ob1 < b1) || (ob1 == b1 && oi1 < i1);
    float nb2 = fminf(fmaxf(b1, ob1), fminf(b2, ob2));
    float nb1 = take ? ob1 : b1;
    int   ni1 = take ? oi1 : i1;
    if (l < 32) {
        tops[(size_t)n * KSP + ks] = make_float2(nb1, nb2);
        topi[(size_t)n * KSP + ks] = ni1;
    }
}

// ---------------------------------------------------------------------------
// Merge the KSP k-split top-2 entries per row; flag near-ties.
// ks ascending = code ranges ascending; strict '<' + index tie-break keeps
// np.argmin lowest-index semantics.
// ---------------------------------------------------------------------------
__global__ __launch_bounds__(256)
void ksplit_merge_kernel(const float2* __restrict__ tops, const int* __restrict__ topi,
                         int* __restrict__ idx_out, float* __restrict__ idxf_out,
                         int* __restrict__ nflag, int* __restrict__ flags, float tau) {
    const int n = blockIdx.x * 256 + threadIdx.x;
    float2 e0 = tops[(size_t)n * KSP + 0];
    float b1 = e0.x, b2 = e0.y;
    int   bi = topi[(size_t)n * KSP + 0];
    #pragma unroll
    for (int j = 1; j < KSP; ++j) {
        float2 ej = tops[(size_t)n * KSP + j];
        int    ij = topi[(size_t)n * KSP + j];
        bool take = (ej.x < b1) || (ej.x == b1 && ij < bi);
        b2 = fminf(fminf(b2, ej.y), take ? b1 : ej.x);
        b1 = take ? ej.x : b1;
        bi = take ? ij   : bi;
    }
    idx_out[n]  = bi;
    idxf_out[n] = (float)bi;
    if (b2 - b1 < tau) {
        int p = atomicAdd(nflag, 1);
        flags[p] = n;
    }
}

// ---------------------------------------------------------------------------
// Inverted-loop exact fixup, 16 row-stripes, 8-row batching (round-13 body,
// audited: coverage 512 cbblk x 16 stripes covers every (f,cbblk); writes
// scr[f*512+cbblk] disjoint; order-independent under flag permutation).
// ---------------------------------------------------------------------------
__global__ __launch_bounds__(256)
void fix1_kernel(const float* __restrict__ ze, const float* __restrict__ cb,
                 const float* __restrict__ c2, const float* __restrict__ x2,
                 const int* __restrict__ nflag, const int* __restrict__ flags,
                 float* __restrict__ scr_s, int* __restrict__ scr_i, int cap) {
    __shared__ float sz[RB][D];        // 8 KB
    __shared__ float sbest[RB][16];
    const int tid     = threadIdx.x;
    const int cl      = tid >> 4;
    const int dt      = tid & 15;
    const int cbblk   = blockIdx.x & 511;
    const int stripe  = blockIdx.x >> 9;
    const int nstripe = gridDim.x >> 9;    // 16
    const int code    = cbblk * 16 + cl;
    const int nf      = min(nflag[0], cap);
    if (nf == 0) return;
    const int perStripe = (nf - stripe + nstripe - 1) / nstripe;
    if (perStripe <= 0) return;
    // hoist this block's cb slice into fp64 registers (once per block)
    double cbr[16];
    {
        const float* crp = cb + (size_t)code * D + dt;
        #pragma unroll
        for (int j = 0; j < 16; ++j) cbr[j] = (double)crp[16 * j];
    }
    const float cc = c2[code];
    for (int it = 0; it < perStripe; it += RB) {
        __syncthreads();                       // prev batch's scan done
        #pragma unroll
        for (int r = 0; r < RB; ++r) {
            if (it + r < perStripe) {
                const int row = flags[stripe + nstripe * (it + r)];
                sz[r][tid] = ze[(size_t)row * D + tid];
            }
        }
        __syncthreads();                       // sz visible
        #pragma unroll
        for (int r = 0; r < RB; ++r) {
            if (it + r < perStripe) {
                double dot = 0.0;
                #pragma unroll
                for (int j = 0; j < 16; ++j)
                    dot = fma((double)sz[r][dt + 16 * j], cbr[j], dot);
                #pragma unroll
                for (int o = 1; o < 16; o <<= 1)
                    dot += __shfl_xor(dot, o);
                if (dt == 0) {
                    const int f = stripe + nstripe * (it + r);
                    float P  = (float)dot;
                    float t3 = __fadd_rn(x2[flags[f]], __fmul_rn(-2.0f, P));
                    sbest[r][cl] = __fadd_rn(t3, cc);
                }
            }
        }
        __syncthreads();                       // sbest visible
        if (tid < RB && it + tid < perStripe) {
            const int f = stripe + nstripe * (it + tid);
            float bs = sbest[tid][0]; int bc = 0;
            #pragma unroll
            for (int c = 1; c < 16; ++c)
                if (sbest[tid][c] < bs) { bs = sbest[tid][c]; bc = c; }
            scr_s[(size_t)f * 512 + cbblk] = bs;
            scr_i[(size_t)f * 512 + cbblk] = cbblk * 16 + bc;
        }
    }
}

__global__ __launch_bounds__(256)
void fix2_kernel(const int* __restrict__ nflag, const int* __restrict__ flags,
                 const float* __restrict__ scr_s, const int* __restrict__ scr_i,
                 int* __restrict__ idx_out, float* __restrict__ idxf_out, int cap) {
    __shared__ float ss[256];
    __shared__ int   si[256];
    const int tid = threadIdx.x;
    const int nf  = min(nflag[0], cap);
    for (int f = blockIdx.x; f < nf; f += gridDim.x) {
        float s0 = scr_s[(size_t)f * 512 + tid];
        int   j0 = scr_i[(size_t)f * 512 + tid];
        float s1 = scr_s[(size_t)f * 512 + 256 + tid];
        int   j1 = scr_i[(size_t)f * 512 + 256 + tid];
        bool take = (s1 < s0) || (s1 == s0 && j1 < j0);
        ss[tid] = take ? s1 : s0;
        si[tid] = take ? j1 : j0;
        __syncthreads();
        for (int o = 128; o; o >>= 1) {
            if (tid < o) {
                if (ss[tid + o] < ss[tid] ||
                    (ss[tid + o] == ss[tid] && si[tid + o] < si[tid])) {
                    ss[tid] = ss[tid + o]; si[tid] = si[tid + o];
                }
            }
            __syncthreads();
        }
        if (tid == 0) {
            const int row = flags[f];
            idx_out[row]  = si[0];
            idxf_out[row] = (float)si[0];
        }
        __syncthreads();
    }
}

// ---------------------------------------------------------------------------
// FALLBACK (round-3 verified): fp32 vector GEMM + top-2, fp64 fixup.
// ---------------------------------------------------------------------------
__global__ __launch_bounds__(512)
void argmin_fp32_kernel(const float* __restrict__ ze, const float* __restrict__ cb,
                        const float* __restrict__ c2,
                        int* __restrict__ idx_out, float* __restrict__ idxf_out,
                        int* __restrict__ nflag, int* __restrict__ flags) {
    __shared__ float smem[12672];
    float* a_s = smem;
    float* b_s = smem + 32 * 128;
    const int tid  = threadIdx.x;
    const int tx   = tid & 31;
    const int ty   = tid >> 5;
    const int row0 = blockIdx.x * 128;
    float b1[8], b2[8];
    int   i1[8];
    #pragma unroll
    for (int r = 0; r < 8; ++r) { b1[r] = 3.4e38f; b2[r] = 3.4e38f; i1[r] = 0; }
    for (int kt = 0; kt < K; kt += 256) {
        float acc[8][8];
        #pragma unroll
        for (int r = 0; r < 8; ++r)
            #pragma unroll
            for (int c = 0; c < 8; ++c) acc[r][c] = 0.0f;
        for (int dc = 0; dc < D; dc += 32) {
            __syncthreads();
            #pragma unroll
            for (int j = 0; j < 2; ++j) {
                int p = tid + j * 512, ar = p >> 3, ad = (p & 7) << 2;
                float4 v = *reinterpret_cast<const float4*>(&ze[(size_t)(row0 + ar) * D + dc + ad]);
                a_s[(ad + 0) * 128 + ar] = v.x; a_s[(ad + 1) * 128 + ar] = v.y;
                a_s[(ad + 2) * 128 + ar] = v.z; a_s[(ad + 3) * 128 + ar] = v.w;
            }
            #pragma unroll
            for (int j = 0; j < 4; ++j) {
                int p = tid + j * 512, br = p >> 3, bd = (p & 7) << 2;
                float4 v = *reinterpret_cast<const float4*>(&cb[(size_t)(kt + br) * D + dc + bd]);
                b_s[(bd + 0) * 256 + br] = v.x; b_s[(bd + 1) * 256 + br] = v.y;
                b_s[(bd + 2) * 256 + br] = v.z; b_s[(bd + 3) * 256 + br] = v.w;
            }
            __syncthreads();
            #pragma unroll 4
            for (int d = 0; d < 32; ++d) {
                float4 a0  = *reinterpret_cast<const float4*>(&a_s[d * 128 + ty * 4]);
                float4 a1  = *reinterpret_cast<const float4*>(&a_s[d * 128 + 64 + ty * 4]);
                float4 b0  = *reinterpret_cast<const float4*>(&b_s[d * 256 + tx * 4]);
                float4 b1v = *reinterpret_cast<const float4*>(&b_s[d * 256 + 128 + tx * 4]);
                float av[8] = {a0.x, a0.y, a0.z, a0.w, a1.x, a1.y, a1.z, a1.w};
                float bv[8] = {b0.x, b0.y, b0.z, b0.w, b1v.x, b1v.y, b1v.z, b1v.w};
                #pragma unroll
                for (int r = 0; r < 8; ++r)
                    #pragma unroll
                    for (int c = 0; c < 8; ++c)
                        acc[r][c] = fmaf(av[r], bv[c], acc[r][c]);
            }
        }
        float4 cs0 = *reinterpret_cast<const float4*>(&c2[kt + tx * 4]);
        float4 cs1 = *reinterpret_cast<const float4*>(&c2[kt + 128 + tx * 4]);
        float cv[8] = {cs0.x, cs0.y, cs0.z, cs0.w, cs1.x, cs1.y, cs1.z, cs1.w};
        #pragma unroll
        for (int r = 0; r < 8; ++r)
            #pragma unroll
            for (int c = 0; c < 8; ++c) {
                int col = kt + ((c < 4) ? (tx * 4 + c) : (128 + tx * 4 + (c - 4)));
                float s = fmaf(-2.0f, acc[r][c], cv[c]);
                if (s < b1[r]) { b2[r] = b1[r]; b1[r] = s; i1[r] = col; }
                else if (s < b2[r]) { b2[r] = s; }
            }
    }
    __syncthreads();
    float* rs1 = smem;
    int*   ri  = (int*)(smem + 4224);
    float* rs2 = smem + 8448;
    #pragma unroll
    for (int r = 0; r < 8; ++r) {
        int lrow = (r >> 2) * 64 + ty * 4 + (r & 3);
        rs1[lrow * 33 + tx] = b1[r]; ri[lrow * 33 + tx] = i1[r]; rs2[lrow * 33 + tx] = b2[r];
    }
    __syncthreads();
    if (tid < 128) {
        float B1 = 3.4e38f, B2 = 3.4e38f;
        int I1 = 0;
        #pragma unroll 4
        for (int t = 0; t < 32; ++t) {
            float s1 = rs1[tid * 33 + t]; int j1 = ri[tid * 33 + t]; float s2 = rs2[tid * 33 + t];
            if (s1 < B1 || (s1 == B1 && j1 < I1)) { B2 = fminf(B2, B1); B1 = s1; I1 = j1; }
            else B2 = fminf(B2, s1);
            B2 = fminf(B2, s2);
        }
        int grow = row0 + tid;
        idx_out[grow] = I1;
        idxf_out[grow] = (float)I1;
        if (B2 - B1 < TAU_OLD) { int p = atomicAdd(nflag, 1); flags[p] = grow; }
    }
}

__global__ __launch_bounds__(256)
void fix_old_kernel(const float* __restrict__ ze, const float* __restrict__ cb,
                    const float* __restrict__ c2, const float* __restrict__ x2,
                    const int* __restrict__ nflag, const int* __restrict__ flags,
                    int* __restrict__ idx_out, float* __restrict__ idxf_out) {
    __shared__ __align__(16) float sx[D];
    __shared__ float sbest[256];
    __shared__ int   sidx[256];
    const int tid = threadIdx.x;
    const int n   = nflag[0];
    for (int f = blockIdx.x; f < n; f += gridDim.x) {
        __syncthreads();
        const int row = flags[f];
        sx[tid] = ze[(size_t)row * D + tid];
        const float x2r = x2[row];
        __syncthreads();
        const float4* sx4 = reinterpret_cast<const float4*>(sx);
        float best = 3.4e38f; int bi = K;
        for (int k = tid; k < K; k += 256) {
            const float4* cbr = reinterpret_cast<const float4*>(&cb[(size_t)k * D]);
            double dot = 0.0;
            #pragma unroll 8
            for (int d4 = 0; d4 < D / 4; ++d4) {
                float4 c = cbr[d4]; float4 x = sx4[d4];
                dot = fma((double)x.x, (double)c.x, dot);
                dot = fma((double)x.y, (double)c.y, dot);
                dot = fma((double)x.z, (double)c.z, dot);
                dot = fma((double)x.w, (double)c.w, dot);
            }
            float P  = (float)dot;
            float t3 = __fadd_rn(x2r, __fmul_rn(-2.0f, P));
            float t4 = __fadd_rn(t3, c2[k]);
            if (t4 < best || (t4 == best && k < bi)) { best = t4; bi = k; }
        }
        sbest[tid] = best; sidx[tid] = bi;
        __syncthreads();
        for (int o = 128; o; o >>= 1) {
            if (tid < o) {
                if (sbest[tid + o] < sbest[tid] ||
                    (sbest[tid + o] == sbest[tid] && sidx[tid + o] < sidx[tid])) {
                    sbest[tid] = sbest[tid + o]; sidx[tid] = sidx[tid + o];
                }
            }
            __syncthreads();
        }
        if (tid == 0) { idx_out[row] = sidx[0]; idxf_out[row] = (float)sidx[0]; }
    }
}

// ---------------------------------------------------------------------------
// gather z_q = cb[idx] + loss reduction (deterministic two-stage)
// ---------------------------------------------------------------------------
__global__ __launch_bounds__(256)
void gather_loss_kernel(const float* __restrict__ ze, const float* __restrict__ cb,
                        const int* __restrict__ idx, float* __restrict__ zq,
                        float* __restrict__ partial) {
    const int tid  = threadIdx.x;
    const int w    = tid >> 6;
    const int lane = tid & 63;
    const int n    = blockIdx.x * 4 + w;
    const int k    = idx[n];
    float4 q = *reinterpret_cast<const float4*>(&cb[(size_t)k * D + lane * 4]);
    float4 z = *reinterpret_cast<const float4*>(&ze[(size_t)n * D + lane * 4]);
    *reinterpret_cast<float4*>(&zq[(size_t)n * D + lane * 4]) = q;
    float dx = z.x - q.x, dy = z.y - q.y, dz = z.z - q.z, dw = z.w - q.w;
    float s = dx * dx + dy * dy + dz * dz + dw * dw;
    #pragma unroll
    for (int o = 32; o; o >>= 1) s += __shfl_down(s, o);
    __shared__ float ws4[4];
    if (lane == 0) ws4[w] = s;
    __syncthreads();
    if (tid == 0) partial[blockIdx.x] = ws4[0] + ws4[1] + ws4[2] + ws4[3];
}

__global__ __launch_bounds__(256)
void final_loss_kernel(const float* __restrict__ partial, float* __restrict__ out) {
    __shared__ float sm[256];
    const int tid = threadIdx.x;
    float s = 0.0f;
    for (int i = tid; i < 8192; i += 256) s += partial[i];
    sm[tid] = s;
    __syncthreads();
    #pragma unroll
    for (int o = 128; o; o >>= 1) {
        if (tid < o) sm[tid] += sm[tid + o];
        __syncthreads();
    }
    if (tid == 0)
        out[0] = sm[0] * (1.0f + BETA) / (float)(NROWS * D);
}

// ---------------------------------------------------------------------------
extern "C" void kernel_launch(void* const* d_in, const int* in_sizes, int n_in,
                              void* d_out, int out_size, void* d_ws, size_t ws_size,
                              hipStream_t stream) {
    const float* ze = (const float*)d_in[0];
    const float* cb = (const float*)d_in[1];

    float* out  = (float*)d_out;
    float* zq   = out;
    float* idxf = out + (size_t)NROWS * D;
    float* loss = out + (size_t)NROWS * D + NROWS;

    char* ws = (char*)d_ws;
    float*  c2      = (float*) (ws);
    float*  x2      = (float*) (ws + 32768);
    int*    idx     = (int*)   (ws + 163840);
    float*  partial = (float*) (ws + 294912);
    int*    nflag   = (int*)   (ws + 327680);
    int*    flags   = (int*)   (ws + 327696);        // ends 458768
    float2* tops    = (float2*)(ws + 458768);        // KSP=4: 1 MB -> 1507344
    int*    topi    = (int*)   (ws + 1507344);       // 512 KB -> 2031632
    unsigned short* cbp = (unsigned short*)(ws + 2031632);   // 4.2 MB -> 6225936
    float*  scr_s   = (float*) (ws + 9633808);
    const size_t scr_base = 9633808;

    const size_t need_min = scr_base + (size_t)2048 * 4096;
    const bool newpath = ws_size >= need_min;
    int cap = 0;
    int* scr_i = nullptr;
    if (newpath) {
        size_t avail = (ws_size - scr_base) / 4096;
        cap = (int)(avail > 8192 ? 8192 : avail);
        scr_i = (int*)(ws + scr_base + (size_t)cap * 2048);
    }

    hipMemsetAsync(nflag, 0, sizeof(int), stream);
    hipLaunchKernelGGL(np_sumsq_kernel, dim3(K / 4), dim3(256), 0, stream, cb, c2, K);

    if (newpath) {
        hipLaunchKernelGGL(pack_cb_kernel,     dim3(256), dim3(256), 0, stream, cb, cbp);
        hipLaunchKernelGGL(mfma_argmin_kernel, dim3((NROWS / 128) * KSP), dim3(256), 0, stream,
                           ze, cbp, c2, tops, topi);
        hipLaunchKernelGGL(ksplit_merge_kernel, dim3(NROWS / 256), dim3(256), 0, stream,
                           tops, topi, idx, idxf, nflag, flags, TAU_NEW);
        hipLaunchKernelGGL(np_sumsq_flagged_kernel, dim3(256), dim3(64), 0, stream,
                           ze, nflag, flags, x2, cap);
        hipLaunchKernelGGL(fix1_kernel, dim3(8192), dim3(256), 0, stream,
                           ze, cb, c2, x2, nflag, flags, scr_s, scr_i, cap);
        hipLaunchKernelGGL(fix2_kernel, dim3(128), dim3(256), 0, stream,
                           nflag, flags, scr_s, scr_i, idx, idxf, cap);
    } else {
        hipLaunchKernelGGL(argmin_fp32_kernel, dim3(NROWS / 128), dim3(512), 0, stream,
                           ze, cb, c2, idx, idxf, nflag, flags);
        hipLaunchKernelGGL(np_sumsq_flagged_kernel, dim3(128), dim3(64), 0, stream,
                           ze, nflag, flags, x2, NROWS);
        hipLaunchKernelGGL(fix_old_kernel, dim3(256), dim3(256), 0, stream,
                           ze, cb, c2, x2, nflag, flags, idx, idxf);
    }

    hipLaunchKernelGGL(gather_loss_kernel, dim3(NROWS / 4), dim3(256), 0, stream,
                       ze, cb, idx, zq, partial);
    hipLaunchKernelGGL(final_loss_kernel, dim3(1), dim3(256), 0, stream,
                       partial, loss);
}